// Round 6
// baseline (661.572 us; speedup 1.0000x reference)
//
#include <hip/hip_runtime.h>

// decoderLayer B=8, L=1024, E=1024, H=16, dk=64. fp32 I/O, bf16 internals,
// fp32 accum via bf16 MFMA 16x16x32. NEW this round (mattn rewrite): barrier-
// free attention. K/V are L2-resident (128KB per (b,h)) -> no LDS staging, no
// barriers, no vmcnt; QK/PV fragments loaded direct from global. Only the
// wave-private P buffer stays in LDS. KVBLK=128, mt-outer (VGPR-lean),
// deferred l-reduction (one shuffle-reduce at end, not per tile), wave-uniform
// mask fast-path, exp2 softmax, defer-rescale, heavy-first causal order.
// Launcher reverted to round-3 split (attribution). mgemm/prep/ln unchanged.

typedef unsigned short u16;
typedef unsigned int u32;
typedef __attribute__((ext_vector_type(8))) short bf16x8;
typedef __attribute__((ext_vector_type(4))) float f32x4;

#define Bv 8
#define Lv 1024
#define Ev 1024
#define Hv 16
#define DKv 64
#define Mv (Bv * Lv)

#if defined(__has_builtin)
# if __has_builtin(__builtin_amdgcn_global_load_lds)
#  define HAS_GLL 1
# endif
#endif
#ifndef HAS_GLL
# define HAS_GLL 0
#endif

#if HAS_GLL
__device__ __forceinline__ void gll16(const u16* g, u16* l) {
    __builtin_amdgcn_global_load_lds(
        (const __attribute__((address_space(1))) void*)(unsigned long long)(g),
        (__attribute__((address_space(3))) void*)(unsigned)(unsigned long long)(l),
        16, 0, 0);
}
#endif

#define FENCE() asm volatile("" ::: "memory")

__device__ __forceinline__ u16 f2bf(float f) {
    u32 u = __float_as_uint(f);
    u += 0x7fffu + ((u >> 16) & 1u);
    return (u16)(u >> 16);
}
__device__ __forceinline__ u32 pack2(float a, float b) {
    u32 ua = __float_as_uint(a); ua += 0x7fffu + ((ua >> 16) & 1u);
    u32 ub = __float_as_uint(b); ub += 0x7fffu + ((ub >> 16) & 1u);
    return (ua >> 16) | (ub & 0xffff0000u);
}
__device__ __forceinline__ float bf_lo(u32 u) { return __uint_as_float(u << 16); }
__device__ __forceinline__ float bf_hi(u32 u) { return __uint_as_float(u & 0xffff0000u); }

// ---- fused prep: conv x, conv ctx, 6 attn-weight transposes, 2 fc transposes.
//      Routed by blockIdx.x; 256 threads. ----
__global__ __launch_bounds__(256) void prep_k(
    const float* __restrict__ x, const float* __restrict__ ctx,
    const float* __restrict__ wq1, const float* __restrict__ wk1, const float* __restrict__ wv1,
    const float* __restrict__ wq2, const float* __restrict__ wk2, const float* __restrict__ wv2,
    const float* __restrict__ f1, const float* __restrict__ f2,
    u16* __restrict__ xb, u16* __restrict__ cb, u16* __restrict__ WT) {
    const int id = blockIdx.x, t = threadIdx.x;
    if (id < 16384) { // conv x / ctx
        const float* s = (id < 8192) ? x : ctx;
        u16* d = (id < 8192) ? xb : cb;
        const int i4 = ((id & 8191) * 256 + t) * 4;
        float4 v = *(const float4*)(s + i4);
        uint2 o = {pack2(v.x, v.y), pack2(v.z, v.w)};
        *(uint2*)(d + i4) = o;
        return;
    }
    __shared__ float tl[32][33];
    const int tx = t & 31, ty = t >> 5;
    if (id < 16384 + 6144) { // attn weight (H,E,dk) -> Wt[h*64+d][e]
        const int wi = (id - 16384) >> 10;
        const int tile = (id - 16384) & 1023;
        const float* s = (wi == 0) ? wq1 : (wi == 1) ? wk1 : (wi == 2) ? wv1
                       : (wi == 3) ? wq2 : (wi == 4) ? wk2 : wv2;
        u16* d = WT + (size_t)wi * Ev * Ev;
        const int h = tile >> 6, rem = tile & 63;
        const int d0 = (rem & 1) * 32, e0 = (rem >> 1) * 32;
#pragma unroll
        for (int i = 0; i < 4; i++)
            tl[ty + i * 8][tx] = s[(size_t)h * Ev * DKv + (size_t)(e0 + ty + i * 8) * DKv + d0 + tx];
        __syncthreads();
#pragma unroll
        for (int i = 0; i < 4; i++)
            d[(size_t)(h * DKv + d0 + ty + i * 8) * Ev + e0 + tx] = f2bf(tl[tx][ty + i * 8]);
    } else { // fc weight (E,E)[k][n] -> Wt[n][k]
        const int wi = (id - 16384 - 6144) >> 10;
        const int tile = (id - 16384 - 6144) & 1023;
        const float* s = wi ? f2 : f1;
        u16* d = WT + (size_t)(6 + wi) * Ev * Ev;
        const int n0 = (tile & 31) * 32, k0 = (tile >> 5) * 32;
#pragma unroll
        for (int i = 0; i < 4; i++)
            tl[ty + i * 8][tx] = s[(size_t)(k0 + ty + i * 8) * Ev + n0 + tx];
        __syncthreads();
#pragma unroll
        for (int i = 0; i < 4; i++)
            d[(size_t)(n0 + ty + i * 8) * Ev + k0 + tx] = f2bf(tl[tx][ty + i * 8]);
    }
}

// ---- MFMA GEMM, 128x128 tile, BK=32, 32 KiB LDS dbuf -> 4 blocks/CU.
//      Distance-2 counted-vmcnt pipeline (unchanged from round 3). ----
template <int BIAS, int RELU, int TRANSW>
__global__ __launch_bounds__(256, 4) void mgemm(const u16* __restrict__ A,
                                                const u16* __restrict__ Wt,
                                                const float* __restrict__ bias,
                                                u16* __restrict__ O0, u16* __restrict__ O1,
                                                u16* __restrict__ O2,
                                                const int* __restrict__ lens,
                                                const u16* __restrict__ A2) {
    __shared__ u16 Alds[2][8 * 512];
    __shared__ u16 Blds[2][8 * 512];
    const int tid = threadIdx.x;
    const int w = tid >> 6, l = tid & 63;
    const int lc = l & 15, lq = l >> 4;
    const int row0 = blockIdx.y * 128, col0 = blockIdx.x * 128;
    const int which = col0 >> 10, colL = col0 & 1023;
    u16* C = (which == 0) ? O0 : (which == 1 ? O1 : O2);
    const bool tr = (TRANSW == which);
    const u16* Aop = (A2 != nullptr && which == 2) ? A2 : A;

    int len = lens[row0 >> 10];
    len = min(max(len, 0), Lv);
    if ((row0 & (Lv - 1)) >= len) { // whole 128-row block masked -> zeros
        const int rr = tid >> 1, cc = (tid & 1) * 64;
        u16* p = tr ? C + (size_t)(colL + rr) * Mv + row0 + cc
                    : C + (size_t)(row0 + rr) * Ev + colL + cc;
        uint4 z4 = {0u, 0u, 0u, 0u};
#pragma unroll
        for (int i = 0; i < 8; i++) *(uint4*)(p + i * 8) = z4;
        return;
    }

    const int wm4 = (w >> 1) * 4, wn4 = (w & 1) * 4;
    f32x4 acc[4][4];
#pragma unroll
    for (int i = 0; i < 4; i++)
#pragma unroll
        for (int j = 0; j < 4; j++) acc[i][j] = (f32x4){0.f, 0.f, 0.f, 0.f};

    // wave w stages subtiles {2w, 2w+1} of A and B (16 rows x 32 k each)
    const u16* Ag[2]; const u16* Bg[2];
    int lof[2];
#pragma unroll
    for (int i = 0; i < 2; i++) {
        const int s = 2 * w + i;
        Ag[i] = Aop + (size_t)(row0 + s * 16 + lc) * Ev + lq * 8;
        Bg[i] = Wt  + (size_t)(col0 + s * 16 + lc) * Ev + lq * 8;
        lof[i] = s * 512;
    }

#if HAS_GLL
    // prologue: stage K-tiles 0 and 1 (4 gll16 each; per-wave vmcnt = 8)
#pragma unroll
    for (int i = 0; i < 2; i++) { gll16(Ag[i], &Alds[0][lof[i]]); gll16(Bg[i], &Blds[0][lof[i]]); }
#pragma unroll
    for (int i = 0; i < 2; i++) { gll16(Ag[i] + 32, &Alds[1][lof[i]]); gll16(Bg[i] + 32, &Blds[1][lof[i]]); }

    for (int t = 0; t < 32; ++t) {
        const int p = t & 1;
        // wait for tile t's 4 loads; tile t+1's 4 stay in flight (except tail)
        if (t < 31) asm volatile("s_waitcnt vmcnt(4)" ::: "memory");
        else        asm volatile("s_waitcnt vmcnt(0)" ::: "memory");
        __builtin_amdgcn_s_barrier();   // all waves' tile-t loads published
        FENCE();                        // pin ds_reads after the barrier
        bf16x8 af[4], bfr[4];
#pragma unroll
        for (int mt = 0; mt < 4; mt++)
            af[mt] = *(const bf16x8*)(&Alds[p][(wm4 + mt) * 512 + l * 8]);
#pragma unroll
        for (int nt = 0; nt < 4; nt++)
            bfr[nt] = *(const bf16x8*)(&Blds[p][(wn4 + nt) * 512 + l * 8]);
#pragma unroll
        for (int mt = 0; mt < 4; mt++)
#pragma unroll
            for (int nt = 0; nt < 4; nt++)
                acc[mt][nt] = __builtin_amdgcn_mfma_f32_16x16x32_bf16(
                    af[mt], bfr[nt], acc[mt][nt], 0, 0, 0);
        FENCE();                        // pin ds_reads before the barrier
        __builtin_amdgcn_s_barrier();   // all reads of buf[p] done
        FENCE();                        // pin stage writes after the barrier
        if (t < 30) {                   // stage tile t+2 into freed buf[p]
            const int ko = (t + 2) * 32;
#pragma unroll
            for (int i = 0; i < 2; i++) {
                gll16(Ag[i] + ko, &Alds[p][lof[i]]);
                gll16(Bg[i] + ko, &Blds[p][lof[i]]);
            }
        }
    }
#else
    // fallback (non-gfx950): single-buffer sync staging
    for (int t = 0; t < 32; ++t) {
        const int ko = t * 32;
#pragma unroll
        for (int i = 0; i < 2; i++) {
            *(uint4*)(&Alds[0][lof[i] + l * 8]) = *(const uint4*)(Ag[i] + ko);
            *(uint4*)(&Blds[0][lof[i] + l * 8]) = *(const uint4*)(Bg[i] + ko);
        }
        __syncthreads();
        bf16x8 af[4], bfr[4];
#pragma unroll
        for (int mt = 0; mt < 4; mt++)
            af[mt] = *(const bf16x8*)(&Alds[0][(wm4 + mt) * 512 + l * 8]);
#pragma unroll
        for (int nt = 0; nt < 4; nt++)
            bfr[nt] = *(const bf16x8*)(&Blds[0][(wn4 + nt) * 512 + l * 8]);
#pragma unroll
        for (int mt = 0; mt < 4; mt++)
#pragma unroll
            for (int nt = 0; nt < 4; nt++)
                acc[mt][nt] = __builtin_amdgcn_mfma_f32_16x16x32_bf16(
                    af[mt], bfr[nt], acc[mt][nt], 0, 0, 0);
        __syncthreads();
    }
#endif

    float bv[4];
#pragma unroll
    for (int nt = 0; nt < 4; nt++)
        bv[nt] = BIAS ? bias[colL + wn4 * 16 + nt * 16 + lc] : 0.f;

#pragma unroll
    for (int mt = 0; mt < 4; mt++) {
        const int rowb = row0 + wm4 * 16 + mt * 16 + lq * 4;
#pragma unroll
        for (int nt = 0; nt < 4; nt++) {
            const int col = colL + wn4 * 16 + nt * 16 + lc;
            float v[4];
#pragma unroll
            for (int r = 0; r < 4; r++) {
                float xv = acc[mt][nt][r] + bv[nt];
                if (RELU) xv = fmaxf(xv, 0.f);
                v[r] = (((rowb + r) & (Lv - 1)) >= len) ? 0.f : xv;
            }
            if (tr) {
                uint2 o = {pack2(v[0], v[1]), pack2(v[2], v[3])};
                *(uint2*)(C + (size_t)col * Mv + rowb) = o;
            } else {
#pragma unroll
                for (int r = 0; r < 4; r++)
                    C[(size_t)(rowb + r) * Ev + col] = f2bf(v[r]);
            }
        }
    }
}

// ---- MFMA flash attention, barrier-free. 128 q/block, 4 independent waves
//      (32 q each, 2 m-tiles), 128-key tiles. K/V read DIRECT from global
//      (L2-resident); only wave-private P buffer in LDS. No __syncthreads
//      in the whole kernel body. Wave-uniform mask fast-path, exp2 softmax,
//      defer-rescale, deferred l-reduction, heavy-first causal order. ----
#define SCL 0.18033688f  // 0.125 * log2(e)
template <int CAUSAL>
__global__ __launch_bounds__(256) void mattn(u16* __restrict__ QZ,
                                             const u16* __restrict__ K,
                                             const u16* __restrict__ VT,
                                             const int* __restrict__ lens) {
    __shared__ u16 Pt[4][2048];      // per-wave 16q x 128k bf16 (wave-private)
    const int b = blockIdx.z, h = blockIdx.y;
    const int qb = CAUSAL ? ((int)gridDim.x - 1 - (int)blockIdx.x) : (int)blockIdx.x;
    const int q0 = qb * 128;
    const int tid = threadIdx.x;
    const int w = tid >> 6, l = tid & 63;
    const int lc = l & 15, lq = l >> 4;
    int len = lens[b];
    len = min(max(len, 0), Lv);

    if (q0 >= len) {
        const int zr = tid >> 1, zc = (tid & 1) * 32;
        uint4 z4 = {0u, 0u, 0u, 0u};
        uint4* p = (uint4*)(QZ + (size_t)(b * Lv + q0 + zr) * Ev + h * DKv + zc);
        p[0] = z4; p[1] = z4; p[2] = z4; p[3] = z4;
        return;
    }

    bf16x8 qf[2][2];
#pragma unroll
    for (int mt = 0; mt < 2; mt++)
#pragma unroll
        for (int k2 = 0; k2 < 2; k2++)
            qf[mt][k2] = *(const bf16x8*)(QZ + (size_t)(b * Lv + q0 + w * 32 + mt * 16 + lc) * Ev +
                                          h * DKv + k2 * 32 + lq * 8);

    f32x4 of[2][4];
#pragma unroll
    for (int mt = 0; mt < 2; mt++)
#pragma unroll
        for (int nd = 0; nd < 4; nd++) of[mt][nd] = (f32x4){0.f, 0.f, 0.f, 0.f};
    float mrow[2][4], lrp[2][4];     // lrp = per-lane partial row-sum (deferred reduce)
#pragma unroll
    for (int mt = 0; mt < 2; mt++)
#pragma unroll
        for (int r = 0; r < 4; r++) { mrow[mt][r] = -1e30f; lrp[mt][r] = 0.f; }

    // direct-fragment base pointers (same algebra the round-3 stager used)
    const u16* Kbase = K  + (size_t)(b * Lv + lc) * Ev + h * DKv + lq * 8;
    const u16* Vbase = VT + (size_t)(h * DKv + lc) * Mv + (size_t)b * Lv + lq * 8;
    u16* Pw = Pt[w];

    const int jend = CAUSAL ? min(len, q0 + 128) : len;
    const int ntiles = (jend + 127) >> 7;

    for (int kt = 0; kt < ntiles; kt++) {
        const int koff = kt * 128;
#pragma unroll
        for (int mt = 0; mt < 2; mt++) {
            const int iqbase = q0 + w * 32 + mt * 16;
            // QK^T: fragments direct from global (L2-hit)
            f32x4 sf[8];
#pragma unroll
            for (int nt = 0; nt < 8; nt++) {
                const u16* kp = Kbase + (size_t)(koff + nt * 16) * Ev;
                bf16x8 kf0 = *(const bf16x8*)(kp);
                bf16x8 kf1 = *(const bf16x8*)(kp + 32);
                f32x4 s = (f32x4){0.f, 0.f, 0.f, 0.f};
                s = __builtin_amdgcn_mfma_f32_16x16x32_bf16(qf[mt][0], kf0, s, 0, 0, 0);
                s = __builtin_amdgcn_mfma_f32_16x16x32_bf16(qf[mt][1], kf1, s, 0, 0, 0);
                sf[nt] = s;
            }

            float tmax[4] = {-1e30f, -1e30f, -1e30f, -1e30f};
            const bool full = (koff + 128 <= len) && (!CAUSAL || (koff + 127 <= iqbase));
            if (full) {
#pragma unroll
                for (int nt = 0; nt < 8; nt++)
#pragma unroll
                    for (int r = 0; r < 4; r++) {
                        float e = sf[nt][r] * SCL;
                        sf[nt][r] = e;
                        tmax[r] = fmaxf(tmax[r], e);
                    }
            } else {
#pragma unroll
                for (int nt = 0; nt < 8; nt++) {
                    const int jj = koff + nt * 16 + lc;
                    const bool jv = jj < len;
#pragma unroll
                    for (int r = 0; r < 4; r++) {
                        const int iq = iqbase + lq * 4 + r;
                        const bool valid = jv && (!CAUSAL || jj <= iq);
                        float e = valid ? sf[nt][r] * SCL : -1e30f;
                        sf[nt][r] = e;
                        tmax[r] = fmaxf(tmax[r], e);
                    }
                }
            }
#pragma unroll
            for (int r = 0; r < 4; r++) {
#pragma unroll
                for (int d = 1; d < 16; d <<= 1)
                    tmax[r] = fmaxf(tmax[r], __shfl_xor(tmax[r], d, 64));
            }
            // defer-rescale: only touch mrow / of / lrp when the max grew
            bool grow = false;
#pragma unroll
            for (int r = 0; r < 4; r++) grow = grow || (tmax[r] > mrow[mt][r]);
            if (__any(grow)) {
                float alpha[4];
#pragma unroll
                for (int r = 0; r < 4; r++) {
                    const float mn = fmaxf(mrow[mt][r], tmax[r]);
                    alpha[r] = exp2f(mrow[mt][r] - mn);
                    mrow[mt][r] = mn;
                }
#pragma unroll
                for (int r = 0; r < 4; r++) lrp[mt][r] *= alpha[r];
#pragma unroll
                for (int nd = 0; nd < 4; nd++)
#pragma unroll
                    for (int r = 0; r < 4; r++) of[mt][nd][r] *= alpha[r];
            }
            // exp + per-lane partial sum (cross-lane reduce deferred to end)
#pragma unroll
            for (int nt = 0; nt < 8; nt++)
#pragma unroll
                for (int r = 0; r < 4; r++) {
                    float p2 = exp2f(sf[nt][r] - mrow[mt][r]);
                    sf[nt][r] = p2;
                    lrp[mt][r] += p2;
                }

            // P -> wave-private LDS (frag order), then PV with direct-global V
#pragma unroll
            for (int nt = 0; nt < 8; nt++)
#pragma unroll
                for (int r = 0; r < 4; r++)
                    Pw[(nt >> 1) * 512 +
                       ((2 * (nt & 1) + (lc >> 3)) * 16 + lq * 4 + r) * 8 + (lc & 7)] =
                        f2bf(sf[nt][r]);
#pragma unroll
            for (int km = 0; km < 4; km++) {
                bf16x8 pa = *(const bf16x8*)(Pw + km * 512 + l * 8);
#pragma unroll
                for (int nd = 0; nd < 4; nd++) {
                    bf16x8 vb = *(const bf16x8*)(Vbase + (size_t)(nd * 16) * Mv +
                                                 koff + km * 32);
                    of[mt][nd] = __builtin_amdgcn_mfma_f32_16x16x32_bf16(pa, vb, of[mt][nd], 0, 0, 0);
                }
            }
        }
    }

#pragma unroll
    for (int mt = 0; mt < 2; mt++) {
        float inv[4];
#pragma unroll
        for (int r = 0; r < 4; r++) {
            float ls = lrp[mt][r];
#pragma unroll
            for (int d = 1; d < 16; d <<= 1) ls += __shfl_xor(ls, d, 64);
            const int iq = q0 + w * 32 + mt * 16 + lq * 4 + r;
            inv[r] = (iq < len && ls > 0.f) ? (1.f / ls) : 0.f;
        }
#pragma unroll
        for (int nd = 0; nd < 4; nd++)
#pragma unroll
            for (int r = 0; r < 4; r++)
                QZ[(size_t)(b * Lv + q0 + w * 32 + mt * 16 + lq * 4 + r) * Ev +
                   h * DKv + nd * 16 + lc] = f2bf(of[mt][nd][r] * inv[r]);
    }
}

// ---- residual + LayerNorm, shuffle reduction: out = LN(base + z)*g + b. ----
template <int BASEBF, int OUTF32>
__global__ __launch_bounds__(256) void ln_k(const void* __restrict__ base,
                                            const u16* __restrict__ z,
                                            const float* __restrict__ g,
                                            const float* __restrict__ bta,
                                            void* __restrict__ out) {
    __shared__ float w1[4], w2[4];
    const int row = blockIdx.x, t = threadIdx.x;
    const int w = t >> 6, l = t & 63;
    const int c0 = t * 4;
    float v[4];
    if (BASEBF) {
        uint2 bu = *(const uint2*)((const u16*)base + (size_t)row * Ev + c0);
        v[0] = bf_lo(bu.x); v[1] = bf_hi(bu.x); v[2] = bf_lo(bu.y); v[3] = bf_hi(bu.y);
    } else {
        float4 f = *(const float4*)((const float*)base + (size_t)row * Ev + c0);
        v[0] = f.x; v[1] = f.y; v[2] = f.z; v[3] = f.w;
    }
    uint2 zu = *(const uint2*)(z + (size_t)row * Ev + c0);
    v[0] += bf_lo(zu.x); v[1] += bf_hi(zu.x); v[2] += bf_lo(zu.y); v[3] += bf_hi(zu.y);
    float s1 = v[0] + v[1] + v[2] + v[3];
    float s2 = v[0] * v[0] + v[1] * v[1] + v[2] * v[2] + v[3] * v[3];
#pragma unroll
    for (int d = 1; d < 64; d <<= 1) {
        s1 += __shfl_xor(s1, d, 64);
        s2 += __shfl_xor(s2, d, 64);
    }
    if (l == 0) { w1[w] = s1; w2[w] = s2; }
    __syncthreads();
    s1 = w1[0] + w1[1] + w1[2] + w1[3];
    s2 = w2[0] + w2[1] + w2[2] + w2[3];
    const float mu = s1 * (1.f / Ev);
    const float var = s2 * (1.f / Ev) - mu * mu;
    const float rinv = rsqrtf(fmaxf(var, 0.f) + 1e-5f);
    float4 gv = *(const float4*)(g + c0);
    float4 bv = *(const float4*)(bta + c0);
    float y[4];
    y[0] = (v[0] - mu) * rinv * gv.x + bv.x;
    y[1] = (v[1] - mu) * rinv * gv.y + bv.y;
    y[2] = (v[2] - mu) * rinv * gv.z + bv.z;
    y[3] = (v[3] - mu) * rinv * gv.w + bv.w;
    if (OUTF32) {
        float4 ow = {y[0], y[1], y[2], y[3]};
        *(float4*)((float*)out + (size_t)row * Ev + c0) = ow;
    } else {
        uint2 ow = {pack2(y[0], y[1]), pack2(y[2], y[3])};
        *(uint2*)((u16*)out + (size_t)row * Ev + c0) = ow;
    }
}

extern "C" void kernel_launch(void* const* d_in, const int* in_sizes, int n_in,
                              void* d_out, int out_size, void* d_ws, size_t ws_size,
                              hipStream_t stream) {
    const float* x    = (const float*)d_in[0];
    const float* ctx  = (const float*)d_in[1];
    const int*   lens = (const int*)d_in[2];
    const float* Wq1 = (const float*)d_in[4];
    const float* Wk1 = (const float*)d_in[5];
    const float* Wv1 = (const float*)d_in[6];
    const float* Wq2 = (const float*)d_in[7];
    const float* Wk2 = (const float*)d_in[8];
    const float* Wv2 = (const float*)d_in[9];
    const float* g1 = (const float*)d_in[10], *b1 = (const float*)d_in[11];
    const float* g2 = (const float*)d_in[12], *b2 = (const float*)d_in[13];
    const float* g3 = (const float*)d_in[14], *b3 = (const float*)d_in[15];
    const float* fc1w = (const float*)d_in[16], *fc1b = (const float*)d_in[17];
    const float* fc2w = (const float*)d_in[18], *fc2b = (const float*)d_in[19];

    const size_t WSZ = (size_t)Ev * Ev;
    const size_t MM  = (size_t)Mv * Ev;
    u16* WT = (u16*)d_ws;                // q1,k1,v1,q2,k2,v2,f1,f2 contiguous
    u16* Wtq1 = WT + 0 * WSZ;
    u16* Wtq2 = WT + 3 * WSZ, *Wtv2 = WT + 5 * WSZ;
    u16* Wtf1 = WT + 6 * WSZ, *Wtf2 = WT + 7 * WSZ;
    u16* B1 = WT + 8 * WSZ;
    u16* B2 = B1 + MM;
    u16* B3 = B2 + MM;
    u16* B4 = B3 + MM;
    u16* xb = (u16*)d_out;               // bf16 x/ctx parked in d_out until final LN
    u16* cb = xb + MM;

    dim3 gP(24576), gQKV(24, 64), gQK(16, 64), gG1(8, 64), gA(8, Hv, Bv), gL(Mv);

    prep_k<<<gP, 256, 0, stream>>>(x, ctx, Wq1, Wk1, Wv1, Wq2, Wk2, Wv2, fc1w, fc2w,
                                   xb, cb, WT);

    // self-attention (causal): fused Q/K/V^T projection, then flash
    mgemm<0, 0, 2><<<gQKV, 256, 0, stream>>>(xb, Wtq1, nullptr, B1, B2, B3, lens, nullptr);
    mattn<1><<<gA, 256, 0, stream>>>(B1, B2, B3, lens);                 // Z1 -> B1
    ln_k<0, 0><<<gL, 256, 0, stream>>>(x, B1, g1, b1, B2);              // X1 -> B2

    // cross-attention: fused Q/K from ctx; V^T from X1
    mgemm<0, 0, -1><<<gQK, 256, 0, stream>>>(cb, Wtq2, nullptr, B1, B3, nullptr, lens, nullptr);
    mgemm<0, 0, 0><<<gG1, 256, 0, stream>>>(B2, Wtv2, nullptr, B4, nullptr, nullptr, lens, nullptr);
    mattn<0><<<gA, 256, 0, stream>>>(B1, B3, B4, lens);                 // Z2 -> B1
    ln_k<1, 0><<<gL, 256, 0, stream>>>(B2, B1, g2, b2, B3);             // X2 -> B3

    // FFN
    mgemm<1, 1, -1><<<gG1, 256, 0, stream>>>(B3, Wtf1, fc1b, B1, nullptr, nullptr, lens, nullptr); // H
    mgemm<1, 0, -1><<<gG1, 256, 0, stream>>>(B1, Wtf2, fc2b, B2, nullptr, nullptr, lens, nullptr); // Z3
    ln_k<1, 1><<<gL, 256, 0, stream>>>(B3, B2, g3, b3, d_out);          // final (fp32)
}

// Round 8
// 543.396 us; speedup vs baseline: 1.2175x; 1.2175x over previous
//
#include <hip/hip_runtime.h>

// decoderLayer B=8, L=1024, E=1024, H=16, dk=64. fp32 I/O, bf16 internals,
// fp32 accum via bf16 MFMA 16x16x32. RESUBMIT of round 7 (bench infra failed;
// kernel never measured): round-3 build (513us) with ONLY mattn's softmax
// body changed -- wave-uniform mask fast-path, exp2-domain softmax,
// defer-rescale, deferred l-reduction, heavy-first causal order. mattn
// structure (KVBLK=128, counted-vmcnt dbuf, 80KB LDS), mgemm (BK=32,
// 4 blocks/CU), prep, ln, fused cross-attn launcher: unchanged.
// Round-6 lesson: direct-global MFMA fragments = 16-line strided loads; the
// stager's value is coalescing, not HBM volume. Never de-stage K/V here.

typedef unsigned short u16;
typedef unsigned int u32;
typedef __attribute__((ext_vector_type(8))) short bf16x8;
typedef __attribute__((ext_vector_type(4))) float f32x4;

#define Bv 8
#define Lv 1024
#define Ev 1024
#define Hv 16
#define DKv 64
#define Mv (Bv * Lv)

#if defined(__has_builtin)
# if __has_builtin(__builtin_amdgcn_global_load_lds)
#  define HAS_GLL 1
# endif
#endif
#ifndef HAS_GLL
# define HAS_GLL 0
#endif

#if HAS_GLL
__device__ __forceinline__ void gll16(const u16* g, u16* l) {
    __builtin_amdgcn_global_load_lds(
        (const __attribute__((address_space(1))) void*)(unsigned long long)(g),
        (__attribute__((address_space(3))) void*)(unsigned)(unsigned long long)(l),
        16, 0, 0);
}
#endif

#define FENCE() asm volatile("" ::: "memory")

__device__ __forceinline__ u16 f2bf(float f) {
    u32 u = __float_as_uint(f);
    u += 0x7fffu + ((u >> 16) & 1u);
    return (u16)(u >> 16);
}
__device__ __forceinline__ u32 pack2(float a, float b) {
    u32 ua = __float_as_uint(a); ua += 0x7fffu + ((ua >> 16) & 1u);
    u32 ub = __float_as_uint(b); ub += 0x7fffu + ((ub >> 16) & 1u);
    return (ua >> 16) | (ub & 0xffff0000u);
}
__device__ __forceinline__ float bf_lo(u32 u) { return __uint_as_float(u << 16); }
__device__ __forceinline__ float bf_hi(u32 u) { return __uint_as_float(u & 0xffff0000u); }

// ---- fused prep: conv x, conv ctx, 6 attn-weight transposes, 2 fc transposes.
//      Routed by blockIdx.x; 256 threads. ----
__global__ __launch_bounds__(256) void prep_k(
    const float* __restrict__ x, const float* __restrict__ ctx,
    const float* __restrict__ wq1, const float* __restrict__ wk1, const float* __restrict__ wv1,
    const float* __restrict__ wq2, const float* __restrict__ wk2, const float* __restrict__ wv2,
    const float* __restrict__ f1, const float* __restrict__ f2,
    u16* __restrict__ xb, u16* __restrict__ cb, u16* __restrict__ WT) {
    const int id = blockIdx.x, t = threadIdx.x;
    if (id < 16384) { // conv x / ctx
        const float* s = (id < 8192) ? x : ctx;
        u16* d = (id < 8192) ? xb : cb;
        const int i4 = ((id & 8191) * 256 + t) * 4;
        float4 v = *(const float4*)(s + i4);
        uint2 o = {pack2(v.x, v.y), pack2(v.z, v.w)};
        *(uint2*)(d + i4) = o;
        return;
    }
    __shared__ float tl[32][33];
    const int tx = t & 31, ty = t >> 5;
    if (id < 16384 + 6144) { // attn weight (H,E,dk) -> Wt[h*64+d][e]
        const int wi = (id - 16384) >> 10;
        const int tile = (id - 16384) & 1023;
        const float* s = (wi == 0) ? wq1 : (wi == 1) ? wk1 : (wi == 2) ? wv1
                       : (wi == 3) ? wq2 : (wi == 4) ? wk2 : wv2;
        u16* d = WT + (size_t)wi * Ev * Ev;
        const int h = tile >> 6, rem = tile & 63;
        const int d0 = (rem & 1) * 32, e0 = (rem >> 1) * 32;
#pragma unroll
        for (int i = 0; i < 4; i++)
            tl[ty + i * 8][tx] = s[(size_t)h * Ev * DKv + (size_t)(e0 + ty + i * 8) * DKv + d0 + tx];
        __syncthreads();
#pragma unroll
        for (int i = 0; i < 4; i++)
            d[(size_t)(h * DKv + d0 + ty + i * 8) * Ev + e0 + tx] = f2bf(tl[tx][ty + i * 8]);
    } else { // fc weight (E,E)[k][n] -> Wt[n][k]
        const int wi = (id - 16384 - 6144) >> 10;
        const int tile = (id - 16384 - 6144) & 1023;
        const float* s = wi ? f2 : f1;
        u16* d = WT + (size_t)(6 + wi) * Ev * Ev;
        const int n0 = (tile & 31) * 32, k0 = (tile >> 5) * 32;
#pragma unroll
        for (int i = 0; i < 4; i++)
            tl[ty + i * 8][tx] = s[(size_t)(k0 + ty + i * 8) * Ev + n0 + tx];
        __syncthreads();
#pragma unroll
        for (int i = 0; i < 4; i++)
            d[(size_t)(n0 + ty + i * 8) * Ev + k0 + tx] = f2bf(tl[tx][ty + i * 8]);
    }
}

// ---- MFMA GEMM, 128x128 tile, BK=32, 32 KiB LDS dbuf -> 4 blocks/CU.
//      Distance-2 counted-vmcnt pipeline (unchanged from round 3). ----
template <int BIAS, int RELU, int TRANSW>
__global__ __launch_bounds__(256, 4) void mgemm(const u16* __restrict__ A,
                                                const u16* __restrict__ Wt,
                                                const float* __restrict__ bias,
                                                u16* __restrict__ O0, u16* __restrict__ O1,
                                                u16* __restrict__ O2,
                                                const int* __restrict__ lens,
                                                const u16* __restrict__ A2) {
    __shared__ u16 Alds[2][8 * 512];
    __shared__ u16 Blds[2][8 * 512];
    const int tid = threadIdx.x;
    const int w = tid >> 6, l = tid & 63;
    const int lc = l & 15, lq = l >> 4;
    const int row0 = blockIdx.y * 128, col0 = blockIdx.x * 128;
    const int which = col0 >> 10, colL = col0 & 1023;
    u16* C = (which == 0) ? O0 : (which == 1 ? O1 : O2);
    const bool tr = (TRANSW == which);
    const u16* Aop = (A2 != nullptr && which == 2) ? A2 : A;

    int len = lens[row0 >> 10];
    len = min(max(len, 0), Lv);
    if ((row0 & (Lv - 1)) >= len) { // whole 128-row block masked -> zeros
        const int rr = tid >> 1, cc = (tid & 1) * 64;
        u16* p = tr ? C + (size_t)(colL + rr) * Mv + row0 + cc
                    : C + (size_t)(row0 + rr) * Ev + colL + cc;
        uint4 z4 = {0u, 0u, 0u, 0u};
#pragma unroll
        for (int i = 0; i < 8; i++) *(uint4*)(p + i * 8) = z4;
        return;
    }

    const int wm4 = (w >> 1) * 4, wn4 = (w & 1) * 4;
    f32x4 acc[4][4];
#pragma unroll
    for (int i = 0; i < 4; i++)
#pragma unroll
        for (int j = 0; j < 4; j++) acc[i][j] = (f32x4){0.f, 0.f, 0.f, 0.f};

    // wave w stages subtiles {2w, 2w+1} of A and B (16 rows x 32 k each)
    const u16* Ag[2]; const u16* Bg[2];
    int lof[2];
#pragma unroll
    for (int i = 0; i < 2; i++) {
        const int s = 2 * w + i;
        Ag[i] = Aop + (size_t)(row0 + s * 16 + lc) * Ev + lq * 8;
        Bg[i] = Wt  + (size_t)(col0 + s * 16 + lc) * Ev + lq * 8;
        lof[i] = s * 512;
    }

#if HAS_GLL
    // prologue: stage K-tiles 0 and 1 (4 gll16 each; per-wave vmcnt = 8)
#pragma unroll
    for (int i = 0; i < 2; i++) { gll16(Ag[i], &Alds[0][lof[i]]); gll16(Bg[i], &Blds[0][lof[i]]); }
#pragma unroll
    for (int i = 0; i < 2; i++) { gll16(Ag[i] + 32, &Alds[1][lof[i]]); gll16(Bg[i] + 32, &Blds[1][lof[i]]); }

    for (int t = 0; t < 32; ++t) {
        const int p = t & 1;
        // wait for tile t's 4 loads; tile t+1's 4 stay in flight (except tail)
        if (t < 31) asm volatile("s_waitcnt vmcnt(4)" ::: "memory");
        else        asm volatile("s_waitcnt vmcnt(0)" ::: "memory");
        __builtin_amdgcn_s_barrier();   // all waves' tile-t loads published
        FENCE();                        // pin ds_reads after the barrier
        bf16x8 af[4], bfr[4];
#pragma unroll
        for (int mt = 0; mt < 4; mt++)
            af[mt] = *(const bf16x8*)(&Alds[p][(wm4 + mt) * 512 + l * 8]);
#pragma unroll
        for (int nt = 0; nt < 4; nt++)
            bfr[nt] = *(const bf16x8*)(&Blds[p][(wn4 + nt) * 512 + l * 8]);
#pragma unroll
        for (int mt = 0; mt < 4; mt++)
#pragma unroll
            for (int nt = 0; nt < 4; nt++)
                acc[mt][nt] = __builtin_amdgcn_mfma_f32_16x16x32_bf16(
                    af[mt], bfr[nt], acc[mt][nt], 0, 0, 0);
        FENCE();                        // pin ds_reads before the barrier
        __builtin_amdgcn_s_barrier();   // all reads of buf[p] done
        FENCE();                        // pin stage writes after the barrier
        if (t < 30) {                   // stage tile t+2 into freed buf[p]
            const int ko = (t + 2) * 32;
#pragma unroll
            for (int i = 0; i < 2; i++) {
                gll16(Ag[i] + ko, &Alds[p][lof[i]]);
                gll16(Bg[i] + ko, &Blds[p][lof[i]]);
            }
        }
    }
#else
    // fallback (non-gfx950): single-buffer sync staging
    for (int t = 0; t < 32; ++t) {
        const int ko = t * 32;
#pragma unroll
        for (int i = 0; i < 2; i++) {
            *(uint4*)(&Alds[0][lof[i] + l * 8]) = *(const uint4*)(Ag[i] + ko);
            *(uint4*)(&Blds[0][lof[i] + l * 8]) = *(const uint4*)(Bg[i] + ko);
        }
        __syncthreads();
        bf16x8 af[4], bfr[4];
#pragma unroll
        for (int mt = 0; mt < 4; mt++)
            af[mt] = *(const bf16x8*)(&Alds[0][(wm4 + mt) * 512 + l * 8]);
#pragma unroll
        for (int nt = 0; nt < 4; nt++)
            bfr[nt] = *(const bf16x8*)(&Blds[0][(wn4 + nt) * 512 + l * 8]);
#pragma unroll
        for (int mt = 0; mt < 4; mt++)
#pragma unroll
            for (int nt = 0; nt < 4; nt++)
                acc[mt][nt] = __builtin_amdgcn_mfma_f32_16x16x32_bf16(
                    af[mt], bfr[nt], acc[mt][nt], 0, 0, 0);
        __syncthreads();
    }
#endif

    float bv[4];
#pragma unroll
    for (int nt = 0; nt < 4; nt++)
        bv[nt] = BIAS ? bias[colL + wn4 * 16 + nt * 16 + lc] : 0.f;

#pragma unroll
    for (int mt = 0; mt < 4; mt++) {
        const int rowb = row0 + wm4 * 16 + mt * 16 + lq * 4;
#pragma unroll
        for (int nt = 0; nt < 4; nt++) {
            const int col = colL + wn4 * 16 + nt * 16 + lc;
            float v[4];
#pragma unroll
            for (int r = 0; r < 4; r++) {
                float xv = acc[mt][nt][r] + bv[nt];
                if (RELU) xv = fmaxf(xv, 0.f);
                v[r] = (((rowb + r) & (Lv - 1)) >= len) ? 0.f : xv;
            }
            if (tr) {
                uint2 o = {pack2(v[0], v[1]), pack2(v[2], v[3])};
                *(uint2*)(C + (size_t)col * Mv + rowb) = o;
            } else {
#pragma unroll
                for (int r = 0; r < 4; r++)
                    C[(size_t)(rowb + r) * Ev + col] = f2bf(v[r]);
            }
        }
    }
}

// ---- MFMA flash attention. 128 q/block, 4 waves x 32 q (2 m-tiles), 128-key
//      tiles, K/V dbuf with counted-vmcnt (round-3 structure). Softmax:
//      wave-uniform mask fast-path, exp2 domain, defer-rescale, deferred
//      l-reduction. Heavy-first qb order for causal. ----
#define SCL 0.18033688f  // 0.125 * log2(e)
template <int CAUSAL>
__global__ __launch_bounds__(256) void mattn(u16* __restrict__ QZ,
                                             const u16* __restrict__ K,
                                             const u16* __restrict__ VT,
                                             const int* __restrict__ lens) {
    __shared__ u16 Kt[2][16 * 512];
    __shared__ u16 Vt[2][16 * 512];
    __shared__ u16 Pt[4 * 4 * 512];
    const int b = blockIdx.z, h = blockIdx.y;
    const int qb = CAUSAL ? ((int)gridDim.x - 1 - (int)blockIdx.x) : (int)blockIdx.x;
    const int q0 = qb * 128;
    const int tid = threadIdx.x;
    const int w = tid >> 6, l = tid & 63;
    const int lc = l & 15, lq = l >> 4;
    int len = lens[b];
    len = min(max(len, 0), Lv);

    if (q0 >= len) {
        const int zr = tid >> 1, zc = (tid & 1) * 32;
        uint4 z4 = {0u, 0u, 0u, 0u};
        uint4* p = (uint4*)(QZ + (size_t)(b * Lv + q0 + zr) * Ev + h * DKv + zc);
        p[0] = z4; p[1] = z4; p[2] = z4; p[3] = z4;
        return;
    }

    bf16x8 qf[2][2];
#pragma unroll
    for (int mt = 0; mt < 2; mt++)
#pragma unroll
        for (int k2 = 0; k2 < 2; k2++)
            qf[mt][k2] = *(const bf16x8*)(QZ + (size_t)(b * Lv + q0 + w * 32 + mt * 16 + lc) * Ev +
                                          h * DKv + k2 * 32 + lq * 8);

    f32x4 of[2][4];
#pragma unroll
    for (int mt = 0; mt < 2; mt++)
#pragma unroll
        for (int nd = 0; nd < 4; nd++) of[mt][nd] = (f32x4){0.f, 0.f, 0.f, 0.f};
    float mrow[2][4], lrp[2][4];    // lrp = per-lane partial row-sum (deferred reduce)
#pragma unroll
    for (int mt = 0; mt < 2; mt++)
#pragma unroll
        for (int r = 0; r < 4; r++) { mrow[mt][r] = -1e30f; lrp[mt][r] = 0.f; }

    const u16* Kg[4]; const u16* Vg[4];
    int kof[4], vof[4];
#pragma unroll
    for (int i = 0; i < 4; i++) {
        const int k16 = 2 * w + (i >> 1), d32 = i & 1;
        Kg[i] = K + (size_t)(b * Lv + k16 * 16 + lc) * Ev + h * DKv + d32 * 32 + lq * 8;
        kof[i] = (k16 * 2 + d32) * 512;
        Vg[i] = VT + (size_t)(h * DKv + w * 16 + lc) * Mv + b * Lv + i * 32 + lq * 8;
        vof[i] = (w * 4 + i) * 512;
    }
    u16* Pw = Pt + w * 2048;

    const int jend = CAUSAL ? min(len, q0 + 128) : len;
    const int ntiles = (jend + 127) >> 7;

#if HAS_GLL
#pragma unroll
    for (int i = 0; i < 4; i++) {
        gll16(Kg[i], &Kt[0][kof[i]]);
        gll16(Vg[i], &Vt[0][vof[i]]);
    }
#else
#pragma unroll
    for (int i = 0; i < 4; i++) {
        *(uint4*)(&Kt[0][kof[i] + l * 8]) = *(const uint4*)Kg[i];
        *(uint4*)(&Vt[0][vof[i] + l * 8]) = *(const uint4*)Vg[i];
    }
    __syncthreads();
#endif

    for (int kt = 0; kt < ntiles; kt++) {
        const int p = kt & 1;
        const int koff = kt * 128;
#if HAS_GLL
        if (kt + 1 < ntiles) {
            const int knext = koff + 128;
#pragma unroll
            for (int i = 0; i < 4; i++) {
                gll16(Kg[i] + (size_t)knext * Ev, &Kt[p ^ 1][kof[i]]);
                gll16(Vg[i] + knext, &Vt[p ^ 1][vof[i]]);
            }
            asm volatile("s_waitcnt vmcnt(8)" ::: "memory"); // tile kt done
        } else {
            asm volatile("s_waitcnt vmcnt(0)" ::: "memory");
        }
        __builtin_amdgcn_s_barrier();   // all waves' tile-kt loads published
        FENCE();
#else
        if (kt > 0) {
            const int kprev = koff;
#pragma unroll
            for (int i = 0; i < 4; i++) {
                *(uint4*)(&Kt[p][kof[i] + l * 8]) = *(const uint4*)(Kg[i] + (size_t)kprev * Ev);
                *(uint4*)(&Vt[p][vof[i] + l * 8]) = *(const uint4*)(Vg[i] + kprev);
            }
            __syncthreads();
        }
#endif
        const u16* Kb = &Kt[p][0];
        const u16* Vb = &Vt[p][0];

        f32x4 sf[2][8];
#pragma unroll
        for (int nt = 0; nt < 8; nt++) {
            bf16x8 kf0 = *(const bf16x8*)(Kb + (nt * 2 + 0) * 512 + l * 8);
            bf16x8 kf1 = *(const bf16x8*)(Kb + (nt * 2 + 1) * 512 + l * 8);
#pragma unroll
            for (int mt = 0; mt < 2; mt++) {
                f32x4 s = (f32x4){0.f, 0.f, 0.f, 0.f};
                s = __builtin_amdgcn_mfma_f32_16x16x32_bf16(qf[mt][0], kf0, s, 0, 0, 0);
                s = __builtin_amdgcn_mfma_f32_16x16x32_bf16(qf[mt][1], kf1, s, 0, 0, 0);
                sf[mt][nt] = s;
            }
        }

#pragma unroll
        for (int mt = 0; mt < 2; mt++) {
            const int iqbase = q0 + w * 32 + mt * 16;
            float tmax[4] = {-1e30f, -1e30f, -1e30f, -1e30f};
            // wave-uniform: interior tiles skip per-element masking entirely
            const bool full = (koff + 128 <= len) && (!CAUSAL || (koff + 127 <= iqbase));
            if (full) {
#pragma unroll
                for (int nt = 0; nt < 8; nt++)
#pragma unroll
                    for (int r = 0; r < 4; r++) {
                        float e = sf[mt][nt][r] * SCL;
                        sf[mt][nt][r] = e;
                        tmax[r] = fmaxf(tmax[r], e);
                    }
            } else {
#pragma unroll
                for (int nt = 0; nt < 8; nt++) {
                    const int jj = koff + nt * 16 + lc;
                    const bool jv = jj < len;
#pragma unroll
                    for (int r = 0; r < 4; r++) {
                        const int iq = iqbase + lq * 4 + r;
                        const bool valid = jv && (!CAUSAL || jj <= iq);
                        float e = valid ? sf[mt][nt][r] * SCL : -1e30f;
                        sf[mt][nt][r] = e;
                        tmax[r] = fmaxf(tmax[r], e);
                    }
                }
            }
#pragma unroll
            for (int r = 0; r < 4; r++) {
#pragma unroll
                for (int d = 1; d < 16; d <<= 1)
                    tmax[r] = fmaxf(tmax[r], __shfl_xor(tmax[r], d, 64));
            }
            // defer-rescale: only touch mrow / of / lrp when the max grew
            bool grow = false;
#pragma unroll
            for (int r = 0; r < 4; r++) grow = grow || (tmax[r] > mrow[mt][r]);
            if (__any(grow)) {
                float alpha[4];
#pragma unroll
                for (int r = 0; r < 4; r++) {
                    const float mn = fmaxf(mrow[mt][r], tmax[r]);
                    alpha[r] = exp2f(mrow[mt][r] - mn);
                    mrow[mt][r] = mn;
                }
#pragma unroll
                for (int r = 0; r < 4; r++) lrp[mt][r] *= alpha[r];
#pragma unroll
                for (int nd = 0; nd < 4; nd++)
#pragma unroll
                    for (int r = 0; r < 4; r++) of[mt][nd][r] *= alpha[r];
            }
            // exp + per-lane partial sum (cross-lane reduce deferred to end)
#pragma unroll
            for (int nt = 0; nt < 8; nt++)
#pragma unroll
                for (int r = 0; r < 4; r++) {
                    float p2 = exp2f(sf[mt][nt][r] - mrow[mt][r]);
                    sf[mt][nt][r] = p2;
                    lrp[mt][r] += p2;
                }
        }

#pragma unroll
        for (int mt = 0; mt < 2; mt++) {
#pragma unroll
            for (int nt = 0; nt < 8; nt++)
#pragma unroll
                for (int r = 0; r < 4; r++)
                    Pw[(nt >> 1) * 512 +
                       ((2 * (nt & 1) + (lc >> 3)) * 16 + lq * 4 + r) * 8 + (lc & 7)] =
                        f2bf(sf[mt][nt][r]);
#pragma unroll
            for (int km = 0; km < 4; km++) {
                bf16x8 pa = *(const bf16x8*)(Pw + km * 512 + l * 8);
#pragma unroll
                for (int nd = 0; nd < 4; nd++) {
                    bf16x8 vb = *(const bf16x8*)(Vb + (nd * 4 + km) * 512 + l * 8);
                    of[mt][nd] = __builtin_amdgcn_mfma_f32_16x16x32_bf16(pa, vb, of[mt][nd], 0, 0, 0);
                }
            }
        }
#if HAS_GLL
        FENCE();
        __builtin_amdgcn_s_barrier();   // all reads of buf[p] done before overwrite
        FENCE();
#else
        __syncthreads();
#endif
    }

#pragma unroll
    for (int mt = 0; mt < 2; mt++) {
        float inv[4];
#pragma unroll
        for (int r = 0; r < 4; r++) {
            float ls = lrp[mt][r];
#pragma unroll
            for (int d = 1; d < 16; d <<= 1) ls += __shfl_xor(ls, d, 64);
            const int iq = q0 + w * 32 + mt * 16 + lq * 4 + r;
            inv[r] = (iq < len && ls > 0.f) ? (1.f / ls) : 0.f;
        }
#pragma unroll
        for (int nd = 0; nd < 4; nd++)
#pragma unroll
            for (int r = 0; r < 4; r++)
                QZ[(size_t)(b * Lv + q0 + w * 32 + mt * 16 + lq * 4 + r) * Ev +
                   h * DKv + nd * 16 + lc] = f2bf(of[mt][nd][r] * inv[r]);
    }
}

// ---- residual + LayerNorm, shuffle reduction: out = LN(base + z)*g + b. ----
template <int BASEBF, int OUTF32>
__global__ __launch_bounds__(256) void ln_k(const void* __restrict__ base,
                                            const u16* __restrict__ z,
                                            const float* __restrict__ g,
                                            const float* __restrict__ bta,
                                            void* __restrict__ out) {
    __shared__ float w1[4], w2[4];
    const int row = blockIdx.x, t = threadIdx.x;
    const int w = t >> 6, l = t & 63;
    const int c0 = t * 4;
    float v[4];
    if (BASEBF) {
        uint2 bu = *(const uint2*)((const u16*)base + (size_t)row * Ev + c0);
        v[0] = bf_lo(bu.x); v[1] = bf_hi(bu.x); v[2] = bf_lo(bu.y); v[3] = bf_hi(bu.y);
    } else {
        float4 f = *(const float4*)((const float*)base + (size_t)row * Ev + c0);
        v[0] = f.x; v[1] = f.y; v[2] = f.z; v[3] = f.w;
    }
    uint2 zu = *(const uint2*)(z + (size_t)row * Ev + c0);
    v[0] += bf_lo(zu.x); v[1] += bf_hi(zu.x); v[2] += bf_lo(zu.y); v[3] += bf_hi(zu.y);
    float s1 = v[0] + v[1] + v[2] + v[3];
    float s2 = v[0] * v[0] + v[1] * v[1] + v[2] * v[2] + v[3] * v[3];
#pragma unroll
    for (int d = 1; d < 64; d <<= 1) {
        s1 += __shfl_xor(s1, d, 64);
        s2 += __shfl_xor(s2, d, 64);
    }
    if (l == 0) { w1[w] = s1; w2[w] = s2; }
    __syncthreads();
    s1 = w1[0] + w1[1] + w1[2] + w1[3];
    s2 = w2[0] + w2[1] + w2[2] + w2[3];
    const float mu = s1 * (1.f / Ev);
    const float var = s2 * (1.f / Ev) - mu * mu;
    const float rinv = rsqrtf(fmaxf(var, 0.f) + 1e-5f);
    float4 gv = *(const float4*)(g + c0);
    float4 bv = *(const float4*)(bta + c0);
    float y[4];
    y[0] = (v[0] - mu) * rinv * gv.x + bv.x;
    y[1] = (v[1] - mu) * rinv * gv.y + bv.y;
    y[2] = (v[2] - mu) * rinv * gv.z + bv.z;
    y[3] = (v[3] - mu) * rinv * gv.w + bv.w;
    if (OUTF32) {
        float4 ow = {y[0], y[1], y[2], y[3]};
        *(float4*)((float*)out + (size_t)row * Ev + c0) = ow;
    } else {
        uint2 ow = {pack2(y[0], y[1]), pack2(y[2], y[3])};
        *(uint2*)((u16*)out + (size_t)row * Ev + c0) = ow;
    }
}

extern "C" void kernel_launch(void* const* d_in, const int* in_sizes, int n_in,
                              void* d_out, int out_size, void* d_ws, size_t ws_size,
                              hipStream_t stream) {
    const float* x    = (const float*)d_in[0];
    const float* ctx  = (const float*)d_in[1];
    const int*   lens = (const int*)d_in[2];
    const float* Wq1 = (const float*)d_in[4];
    const float* Wk1 = (const float*)d_in[5];
    const float* Wv1 = (const float*)d_in[6];
    const float* Wq2 = (const float*)d_in[7];
    const float* Wk2 = (const float*)d_in[8];
    const float* Wv2 = (const float*)d_in[9];
    const float* g1 = (const float*)d_in[10], *b1 = (const float*)d_in[11];
    const float* g2 = (const float*)d_in[12], *b2 = (const float*)d_in[13];
    const float* g3 = (const float*)d_in[14], *b3 = (const float*)d_in[15];
    const float* fc1w = (const float*)d_in[16], *fc1b = (const float*)d_in[17];
    const float* fc2w = (const float*)d_in[18], *fc2b = (const float*)d_in[19];

    const size_t WSZ = (size_t)Ev * Ev;
    const size_t MM  = (size_t)Mv * Ev;
    u16* WT = (u16*)d_ws;                // q1,k1,v1,q2,k2,v2,f1,f2 contiguous
    u16* Wtq1 = WT + 0 * WSZ;
    u16* Wtq2 = WT + 3 * WSZ;            // q2|k2|v2 contiguous -> one 24-wide pass
    u16* Wtf1 = WT + 6 * WSZ, *Wtf2 = WT + 7 * WSZ;
    u16* B1 = WT + 8 * WSZ;
    u16* B2 = B1 + MM;
    u16* B3 = B2 + MM;
    u16* B4 = B3 + MM;
    u16* xb = (u16*)d_out;               // bf16 x/ctx parked in d_out until final LN
    u16* cb = xb + MM;

    dim3 gP(24576), gW(24, 64), gG1(8, 64), gA(8, Hv, Bv), gL(Mv);

    prep_k<<<gP, 256, 0, stream>>>(x, ctx, Wq1, Wk1, Wv1, Wq2, Wk2, Wv2, fc1w, fc2w,
                                   xb, cb, WT);

    // self-attention (causal): fused Q/K/V^T projection, then flash
    mgemm<0, 0, 2><<<gW, 256, 0, stream>>>(xb, Wtq1, nullptr, B1, B2, B3, lens, nullptr);
    mattn<1><<<gA, 256, 0, stream>>>(B1, B2, B3, lens);                 // Z1 -> B1
    ln_k<0, 0><<<gL, 256, 0, stream>>>(x, B1, g1, b1, B2);              // X1 -> B2

    // cross-attention: fused Q2/K2 (from ctx) + V2^T (from X1) in ONE pass
    mgemm<0, 0, 2><<<gW, 256, 0, stream>>>(cb, Wtq2, nullptr, B1, B3, B4, lens, B2);
    mattn<0><<<gA, 256, 0, stream>>>(B1, B3, B4, lens);                 // Z2 -> B1
    ln_k<1, 0><<<gL, 256, 0, stream>>>(B2, B1, g2, b2, B3);             // X2 -> B3

    // FFN
    mgemm<1, 1, -1><<<gG1, 256, 0, stream>>>(B3, Wtf1, fc1b, B1, nullptr, nullptr, lens, nullptr); // H
    mgemm<1, 0, -1><<<gG1, 256, 0, stream>>>(B1, Wtf2, fc2b, B2, nullptr, nullptr, lens, nullptr); // Z3
    ln_k<1, 1><<<gL, 256, 0, stream>>>(B3, B2, g3, b3, d_out);          // final (fp32)
}

// Round 9
// 512.992 us; speedup vs baseline: 1.2896x; 1.0593x over previous
//
#include <hip/hip_runtime.h>

// decoderLayer B=8, L=1024, E=1024, H=16, dk=64. fp32 I/O, bf16 internals,
// fp32 accum via bf16 MFMA 16x16x32. This round: RECOMBINE best-measured
// pieces. mgemm = round-3 (BK=32, 32KiB dbuf, 4 blocks/CU, counted vmcnt,
// fences). mattn = round-2 form (KVBLK=128, counted-vmcnt dbuf, NO fences --
// cross-round A/B showed the three FENCE() clobbers cost ~10us/dispatch:
// round-2 mattn <75us vs round-3 85us, only diff = fences). Launcher =
// round-3 fused cross-attn QK|V2. Round-8's softmax rework rejected
// (VGPR 128->136, occupancy halved, net -5us).

typedef unsigned short u16;
typedef unsigned int u32;
typedef __attribute__((ext_vector_type(8))) short bf16x8;
typedef __attribute__((ext_vector_type(4))) float f32x4;

#define Bv 8
#define Lv 1024
#define Ev 1024
#define Hv 16
#define DKv 64
#define Mv (Bv * Lv)

#if defined(__has_builtin)
# if __has_builtin(__builtin_amdgcn_global_load_lds)
#  define HAS_GLL 1
# endif
#endif
#ifndef HAS_GLL
# define HAS_GLL 0
#endif

#if HAS_GLL
__device__ __forceinline__ void gll16(const u16* g, u16* l) {
    __builtin_amdgcn_global_load_lds(
        (const __attribute__((address_space(1))) void*)(unsigned long long)(g),
        (__attribute__((address_space(3))) void*)(unsigned)(unsigned long long)(l),
        16, 0, 0);
}
#endif

#define FENCE() asm volatile("" ::: "memory")

__device__ __forceinline__ u16 f2bf(float f) {
    u32 u = __float_as_uint(f);
    u += 0x7fffu + ((u >> 16) & 1u);
    return (u16)(u >> 16);
}
__device__ __forceinline__ u32 pack2(float a, float b) {
    u32 ua = __float_as_uint(a); ua += 0x7fffu + ((ua >> 16) & 1u);
    u32 ub = __float_as_uint(b); ub += 0x7fffu + ((ub >> 16) & 1u);
    return (ua >> 16) | (ub & 0xffff0000u);
}
__device__ __forceinline__ float bf_lo(u32 u) { return __uint_as_float(u << 16); }
__device__ __forceinline__ float bf_hi(u32 u) { return __uint_as_float(u & 0xffff0000u); }

// ---- fused prep: conv x, conv ctx, 6 attn-weight transposes, 2 fc transposes.
//      Routed by blockIdx.x; 256 threads. ----
__global__ __launch_bounds__(256) void prep_k(
    const float* __restrict__ x, const float* __restrict__ ctx,
    const float* __restrict__ wq1, const float* __restrict__ wk1, const float* __restrict__ wv1,
    const float* __restrict__ wq2, const float* __restrict__ wk2, const float* __restrict__ wv2,
    const float* __restrict__ f1, const float* __restrict__ f2,
    u16* __restrict__ xb, u16* __restrict__ cb, u16* __restrict__ WT) {
    const int id = blockIdx.x, t = threadIdx.x;
    if (id < 16384) { // conv x / ctx
        const float* s = (id < 8192) ? x : ctx;
        u16* d = (id < 8192) ? xb : cb;
        const int i4 = ((id & 8191) * 256 + t) * 4;
        float4 v = *(const float4*)(s + i4);
        uint2 o = {pack2(v.x, v.y), pack2(v.z, v.w)};
        *(uint2*)(d + i4) = o;
        return;
    }
    __shared__ float tl[32][33];
    const int tx = t & 31, ty = t >> 5;
    if (id < 16384 + 6144) { // attn weight (H,E,dk) -> Wt[h*64+d][e]
        const int wi = (id - 16384) >> 10;
        const int tile = (id - 16384) & 1023;
        const float* s = (wi == 0) ? wq1 : (wi == 1) ? wk1 : (wi == 2) ? wv1
                       : (wi == 3) ? wq2 : (wi == 4) ? wk2 : wv2;
        u16* d = WT + (size_t)wi * Ev * Ev;
        const int h = tile >> 6, rem = tile & 63;
        const int d0 = (rem & 1) * 32, e0 = (rem >> 1) * 32;
#pragma unroll
        for (int i = 0; i < 4; i++)
            tl[ty + i * 8][tx] = s[(size_t)h * Ev * DKv + (size_t)(e0 + ty + i * 8) * DKv + d0 + tx];
        __syncthreads();
#pragma unroll
        for (int i = 0; i < 4; i++)
            d[(size_t)(h * DKv + d0 + ty + i * 8) * Ev + e0 + tx] = f2bf(tl[tx][ty + i * 8]);
    } else { // fc weight (E,E)[k][n] -> Wt[n][k]
        const int wi = (id - 16384 - 6144) >> 10;
        const int tile = (id - 16384 - 6144) & 1023;
        const float* s = wi ? f2 : f1;
        u16* d = WT + (size_t)(6 + wi) * Ev * Ev;
        const int n0 = (tile & 31) * 32, k0 = (tile >> 5) * 32;
#pragma unroll
        for (int i = 0; i < 4; i++)
            tl[ty + i * 8][tx] = s[(size_t)(k0 + ty + i * 8) * Ev + n0 + tx];
        __syncthreads();
#pragma unroll
        for (int i = 0; i < 4; i++)
            d[(size_t)(n0 + ty + i * 8) * Ev + k0 + tx] = f2bf(tl[tx][ty + i * 8]);
    }
}

// ---- MFMA GEMM, 128x128 tile, BK=32, 32 KiB LDS dbuf -> 4 blocks/CU.
//      Distance-2 counted-vmcnt pipeline (round-3 form, unchanged). ----
template <int BIAS, int RELU, int TRANSW>
__global__ __launch_bounds__(256, 4) void mgemm(const u16* __restrict__ A,
                                                const u16* __restrict__ Wt,
                                                const float* __restrict__ bias,
                                                u16* __restrict__ O0, u16* __restrict__ O1,
                                                u16* __restrict__ O2,
                                                const int* __restrict__ lens,
                                                const u16* __restrict__ A2) {
    __shared__ u16 Alds[2][8 * 512];
    __shared__ u16 Blds[2][8 * 512];
    const int tid = threadIdx.x;
    const int w = tid >> 6, l = tid & 63;
    const int lc = l & 15, lq = l >> 4;
    const int row0 = blockIdx.y * 128, col0 = blockIdx.x * 128;
    const int which = col0 >> 10, colL = col0 & 1023;
    u16* C = (which == 0) ? O0 : (which == 1 ? O1 : O2);
    const bool tr = (TRANSW == which);
    const u16* Aop = (A2 != nullptr && which == 2) ? A2 : A;

    int len = lens[row0 >> 10];
    len = min(max(len, 0), Lv);
    if ((row0 & (Lv - 1)) >= len) { // whole 128-row block masked -> zeros
        const int rr = tid >> 1, cc = (tid & 1) * 64;
        u16* p = tr ? C + (size_t)(colL + rr) * Mv + row0 + cc
                    : C + (size_t)(row0 + rr) * Ev + colL + cc;
        uint4 z4 = {0u, 0u, 0u, 0u};
#pragma unroll
        for (int i = 0; i < 8; i++) *(uint4*)(p + i * 8) = z4;
        return;
    }

    const int wm4 = (w >> 1) * 4, wn4 = (w & 1) * 4;
    f32x4 acc[4][4];
#pragma unroll
    for (int i = 0; i < 4; i++)
#pragma unroll
        for (int j = 0; j < 4; j++) acc[i][j] = (f32x4){0.f, 0.f, 0.f, 0.f};

    // wave w stages subtiles {2w, 2w+1} of A and B (16 rows x 32 k each)
    const u16* Ag[2]; const u16* Bg[2];
    int lof[2];
#pragma unroll
    for (int i = 0; i < 2; i++) {
        const int s = 2 * w + i;
        Ag[i] = Aop + (size_t)(row0 + s * 16 + lc) * Ev + lq * 8;
        Bg[i] = Wt  + (size_t)(col0 + s * 16 + lc) * Ev + lq * 8;
        lof[i] = s * 512;
    }

#if HAS_GLL
    // prologue: stage K-tiles 0 and 1 (4 gll16 each; per-wave vmcnt = 8)
#pragma unroll
    for (int i = 0; i < 2; i++) { gll16(Ag[i], &Alds[0][lof[i]]); gll16(Bg[i], &Blds[0][lof[i]]); }
#pragma unroll
    for (int i = 0; i < 2; i++) { gll16(Ag[i] + 32, &Alds[1][lof[i]]); gll16(Bg[i] + 32, &Blds[1][lof[i]]); }

    for (int t = 0; t < 32; ++t) {
        const int p = t & 1;
        // wait for tile t's 4 loads; tile t+1's 4 stay in flight (except tail)
        if (t < 31) asm volatile("s_waitcnt vmcnt(4)" ::: "memory");
        else        asm volatile("s_waitcnt vmcnt(0)" ::: "memory");
        __builtin_amdgcn_s_barrier();   // all waves' tile-t loads published
        FENCE();                        // pin ds_reads after the barrier
        bf16x8 af[4], bfr[4];
#pragma unroll
        for (int mt = 0; mt < 4; mt++)
            af[mt] = *(const bf16x8*)(&Alds[p][(wm4 + mt) * 512 + l * 8]);
#pragma unroll
        for (int nt = 0; nt < 4; nt++)
            bfr[nt] = *(const bf16x8*)(&Blds[p][(wn4 + nt) * 512 + l * 8]);
#pragma unroll
        for (int mt = 0; mt < 4; mt++)
#pragma unroll
            for (int nt = 0; nt < 4; nt++)
                acc[mt][nt] = __builtin_amdgcn_mfma_f32_16x16x32_bf16(
                    af[mt], bfr[nt], acc[mt][nt], 0, 0, 0);
        FENCE();                        // pin ds_reads before the barrier
        __builtin_amdgcn_s_barrier();   // all reads of buf[p] done
        FENCE();                        // pin stage writes after the barrier
        if (t < 30) {                   // stage tile t+2 into freed buf[p]
            const int ko = (t + 2) * 32;
#pragma unroll
            for (int i = 0; i < 2; i++) {
                gll16(Ag[i] + ko, &Alds[p][lof[i]]);
                gll16(Bg[i] + ko, &Blds[p][lof[i]]);
            }
        }
    }
#else
    // fallback (non-gfx950): single-buffer sync staging
    for (int t = 0; t < 32; ++t) {
        const int ko = t * 32;
#pragma unroll
        for (int i = 0; i < 2; i++) {
            *(uint4*)(&Alds[0][lof[i] + l * 8]) = *(const uint4*)(Ag[i] + ko);
            *(uint4*)(&Blds[0][lof[i] + l * 8]) = *(const uint4*)(Bg[i] + ko);
        }
        __syncthreads();
        bf16x8 af[4], bfr[4];
#pragma unroll
        for (int mt = 0; mt < 4; mt++)
            af[mt] = *(const bf16x8*)(&Alds[0][(wm4 + mt) * 512 + l * 8]);
#pragma unroll
        for (int nt = 0; nt < 4; nt++)
            bfr[nt] = *(const bf16x8*)(&Blds[0][(wn4 + nt) * 512 + l * 8]);
#pragma unroll
        for (int mt = 0; mt < 4; mt++)
#pragma unroll
            for (int nt = 0; nt < 4; nt++)
                acc[mt][nt] = __builtin_amdgcn_mfma_f32_16x16x32_bf16(
                    af[mt], bfr[nt], acc[mt][nt], 0, 0, 0);
        __syncthreads();
    }
#endif

    float bv[4];
#pragma unroll
    for (int nt = 0; nt < 4; nt++)
        bv[nt] = BIAS ? bias[colL + wn4 * 16 + nt * 16 + lc] : 0.f;

#pragma unroll
    for (int mt = 0; mt < 4; mt++) {
        const int rowb = row0 + wm4 * 16 + mt * 16 + lq * 4;
#pragma unroll
        for (int nt = 0; nt < 4; nt++) {
            const int col = colL + wn4 * 16 + nt * 16 + lc;
            float v[4];
#pragma unroll
            for (int r = 0; r < 4; r++) {
                float xv = acc[mt][nt][r] + bv[nt];
                if (RELU) xv = fmaxf(xv, 0.f);
                v[r] = (((rowb + r) & (Lv - 1)) >= len) ? 0.f : xv;
            }
            if (tr) {
                uint2 o = {pack2(v[0], v[1]), pack2(v[2], v[3])};
                *(uint2*)(C + (size_t)col * Mv + rowb) = o;
            } else {
#pragma unroll
                for (int r = 0; r < 4; r++)
                    C[(size_t)(rowb + r) * Ev + col] = f2bf(v[r]);
            }
        }
    }
}

// ---- MFMA flash attention. 128 q/block, 4 waves x 32 q (2 m-tiles), 128-key
//      tiles, K/V double-buffered with counted-vmcnt (distance-1: issue stage
//      t+1, vmcnt(8), barrier, compute, barrier), P fragment-ordered LDS,
//      online softmax. Round-2 form: NO compiler fences (they cost ~10us). ----
template <int CAUSAL>
__global__ __launch_bounds__(256) void mattn(u16* __restrict__ QZ,
                                             const u16* __restrict__ K,
                                             const u16* __restrict__ VT,
                                             const int* __restrict__ lens) {
    __shared__ u16 Kt[2][16 * 512];
    __shared__ u16 Vt[2][16 * 512];
    __shared__ u16 Pt[4 * 4 * 512];
    const int b = blockIdx.z, h = blockIdx.y, qb = blockIdx.x;
    const int q0 = qb * 128;
    const int tid = threadIdx.x;
    const int w = tid >> 6, l = tid & 63;
    const int lc = l & 15, lq = l >> 4;
    int len = lens[b];
    len = min(max(len, 0), Lv);

    if (q0 >= len) {
        const int zr = tid >> 1, zc = (tid & 1) * 32;
        uint4 z4 = {0u, 0u, 0u, 0u};
        uint4* p = (uint4*)(QZ + (size_t)(b * Lv + q0 + zr) * Ev + h * DKv + zc);
        p[0] = z4; p[1] = z4; p[2] = z4; p[3] = z4;
        return;
    }

    bf16x8 qf[2][2];
#pragma unroll
    for (int mt = 0; mt < 2; mt++)
#pragma unroll
        for (int k2 = 0; k2 < 2; k2++)
            qf[mt][k2] = *(const bf16x8*)(QZ + (size_t)(b * Lv + q0 + w * 32 + mt * 16 + lc) * Ev +
                                          h * DKv + k2 * 32 + lq * 8);

    f32x4 of[2][4];
#pragma unroll
    for (int mt = 0; mt < 2; mt++)
#pragma unroll
        for (int nd = 0; nd < 4; nd++) of[mt][nd] = (f32x4){0.f, 0.f, 0.f, 0.f};
    float mrow[2][4], lrow[2][4];
#pragma unroll
    for (int mt = 0; mt < 2; mt++)
#pragma unroll
        for (int r = 0; r < 4; r++) { mrow[mt][r] = -1e30f; lrow[mt][r] = 0.f; }

    const u16* Kg[4]; const u16* Vg[4];
    int kof[4], vof[4];
#pragma unroll
    for (int i = 0; i < 4; i++) {
        const int k16 = 2 * w + (i >> 1), d32 = i & 1;
        Kg[i] = K + (size_t)(b * Lv + k16 * 16 + lc) * Ev + h * DKv + d32 * 32 + lq * 8;
        kof[i] = (k16 * 2 + d32) * 512;
        Vg[i] = VT + (size_t)(h * DKv + w * 16 + lc) * Mv + b * Lv + i * 32 + lq * 8;
        vof[i] = (w * 4 + i) * 512;
    }
    u16* Pw = Pt + w * 2048;

    const int jend = CAUSAL ? min(len, q0 + 128) : len;
    const int ntiles = (jend + 127) >> 7;

#if HAS_GLL
#pragma unroll
    for (int i = 0; i < 4; i++) {
        gll16(Kg[i], &Kt[0][kof[i]]);
        gll16(Vg[i], &Vt[0][vof[i]]);
    }
#endif
#if !HAS_GLL
#pragma unroll
    for (int i = 0; i < 4; i++) {
        *(uint4*)(&Kt[0][kof[i] + l * 8]) = *(const uint4*)Kg[i];
        *(uint4*)(&Vt[0][vof[i] + l * 8]) = *(const uint4*)Vg[i];
    }
    __syncthreads();
#endif

    for (int kt = 0; kt < ntiles; kt++) {
        const int p = kt & 1;
        const int koff = kt * 128;
#if HAS_GLL
        if (kt + 1 < ntiles) {
            const int knext = koff + 128;
#pragma unroll
            for (int i = 0; i < 4; i++) {
                gll16(Kg[i] + (size_t)knext * Ev, &Kt[p ^ 1][kof[i]]);
                gll16(Vg[i] + knext, &Vt[p ^ 1][vof[i]]);
            }
            asm volatile("s_waitcnt vmcnt(8)" ::: "memory"); // tile kt done
        } else {
            asm volatile("s_waitcnt vmcnt(0)" ::: "memory");
        }
        __builtin_amdgcn_s_barrier();   // all waves' tile-kt loads published
#else
        if (kt > 0) {
            const int kprev = koff;
#pragma unroll
            for (int i = 0; i < 4; i++) {
                *(uint4*)(&Kt[p][kof[i] + l * 8]) = *(const uint4*)(Kg[i] + (size_t)kprev * Ev);
                *(uint4*)(&Vt[p][vof[i] + l * 8]) = *(const uint4*)(Vg[i] + kprev);
            }
            __syncthreads();
        }
#endif
        const u16* Kb = &Kt[p][0];
        const u16* Vb = &Vt[p][0];

        f32x4 sf[2][8];
#pragma unroll
        for (int nt = 0; nt < 8; nt++) {
            bf16x8 kf0 = *(const bf16x8*)(Kb + (nt * 2 + 0) * 512 + l * 8);
            bf16x8 kf1 = *(const bf16x8*)(Kb + (nt * 2 + 1) * 512 + l * 8);
#pragma unroll
            for (int mt = 0; mt < 2; mt++) {
                f32x4 s = (f32x4){0.f, 0.f, 0.f, 0.f};
                s = __builtin_amdgcn_mfma_f32_16x16x32_bf16(qf[mt][0], kf0, s, 0, 0, 0);
                s = __builtin_amdgcn_mfma_f32_16x16x32_bf16(qf[mt][1], kf1, s, 0, 0, 0);
                sf[mt][nt] = s;
            }
        }

        float alpha[2][4];
#pragma unroll
        for (int mt = 0; mt < 2; mt++) {
            float tmax[4] = {-1e30f, -1e30f, -1e30f, -1e30f};
#pragma unroll
            for (int nt = 0; nt < 8; nt++) {
                const int jj = koff + nt * 16 + lc;
                const bool jv = jj < len;
#pragma unroll
                for (int r = 0; r < 4; r++) {
                    const int iq = q0 + w * 32 + mt * 16 + lq * 4 + r;
                    const bool valid = jv && (!CAUSAL || jj <= iq);
                    float e = valid ? sf[mt][nt][r] * 0.125f : -1e30f;
                    sf[mt][nt][r] = e;
                    tmax[r] = fmaxf(tmax[r], e);
                }
            }
#pragma unroll
            for (int r = 0; r < 4; r++) {
#pragma unroll
                for (int d = 1; d < 16; d <<= 1)
                    tmax[r] = fmaxf(tmax[r], __shfl_xor(tmax[r], d, 64));
            }
            float psum[4];
#pragma unroll
            for (int r = 0; r < 4; r++) {
                const float mn = fmaxf(mrow[mt][r], tmax[r]);
                alpha[mt][r] = __expf(mrow[mt][r] - mn);
                mrow[mt][r] = mn;
                psum[r] = 0.f;
            }
#pragma unroll
            for (int nt = 0; nt < 8; nt++)
#pragma unroll
                for (int r = 0; r < 4; r++) {
                    float p2 = __expf(sf[mt][nt][r] - mrow[mt][r]);
                    sf[mt][nt][r] = p2;
                    psum[r] += p2;
                }
#pragma unroll
            for (int r = 0; r < 4; r++) {
#pragma unroll
                for (int d = 1; d < 16; d <<= 1) psum[r] += __shfl_xor(psum[r], d, 64);
                lrow[mt][r] = lrow[mt][r] * alpha[mt][r] + psum[r];
            }
#pragma unroll
            for (int nd = 0; nd < 4; nd++)
#pragma unroll
                for (int r = 0; r < 4; r++) of[mt][nd][r] *= alpha[mt][r];
        }

#pragma unroll
        for (int mt = 0; mt < 2; mt++) {
#pragma unroll
            for (int nt = 0; nt < 8; nt++)
#pragma unroll
                for (int r = 0; r < 4; r++)
                    Pw[(nt >> 1) * 512 +
                       ((2 * (nt & 1) + (lc >> 3)) * 16 + lq * 4 + r) * 8 + (lc & 7)] =
                        f2bf(sf[mt][nt][r]);
#pragma unroll
            for (int km = 0; km < 4; km++) {
                bf16x8 pa = *(const bf16x8*)(Pw + km * 512 + l * 8);
#pragma unroll
                for (int nd = 0; nd < 4; nd++) {
                    bf16x8 vb = *(const bf16x8*)(Vb + (nd * 4 + km) * 512 + l * 8);
                    of[mt][nd] = __builtin_amdgcn_mfma_f32_16x16x32_bf16(pa, vb, of[mt][nd], 0, 0, 0);
                }
            }
        }
#if HAS_GLL
        __builtin_amdgcn_s_barrier();   // all reads of buf[p] done before overwrite
#else
        __syncthreads();
#endif
    }

#pragma unroll
    for (int mt = 0; mt < 2; mt++) {
        float inv[4];
#pragma unroll
        for (int r = 0; r < 4; r++) {
            const int iq = q0 + w * 32 + mt * 16 + lq * 4 + r;
            inv[r] = (iq < len && lrow[mt][r] > 0.f) ? (1.f / lrow[mt][r]) : 0.f;
        }
#pragma unroll
        for (int nd = 0; nd < 4; nd++)
#pragma unroll
            for (int r = 0; r < 4; r++)
                QZ[(size_t)(b * Lv + q0 + w * 32 + mt * 16 + lq * 4 + r) * Ev +
                   h * DKv + nd * 16 + lc] = f2bf(of[mt][nd][r] * inv[r]);
    }
}

// ---- residual + LayerNorm, shuffle reduction: out = LN(base + z)*g + b. ----
template <int BASEBF, int OUTF32>
__global__ __launch_bounds__(256) void ln_k(const void* __restrict__ base,
                                            const u16* __restrict__ z,
                                            const float* __restrict__ g,
                                            const float* __restrict__ bta,
                                            void* __restrict__ out) {
    __shared__ float w1[4], w2[4];
    const int row = blockIdx.x, t = threadIdx.x;
    const int w = t >> 6, l = t & 63;
    const int c0 = t * 4;
    float v[4];
    if (BASEBF) {
        uint2 bu = *(const uint2*)((const u16*)base + (size_t)row * Ev + c0);
        v[0] = bf_lo(bu.x); v[1] = bf_hi(bu.x); v[2] = bf_lo(bu.y); v[3] = bf_hi(bu.y);
    } else {
        float4 f = *(const float4*)((const float*)base + (size_t)row * Ev + c0);
        v[0] = f.x; v[1] = f.y; v[2] = f.z; v[3] = f.w;
    }
    uint2 zu = *(const uint2*)(z + (size_t)row * Ev + c0);
    v[0] += bf_lo(zu.x); v[1] += bf_hi(zu.x); v[2] += bf_lo(zu.y); v[3] += bf_hi(zu.y);
    float s1 = v[0] + v[1] + v[2] + v[3];
    float s2 = v[0] * v[0] + v[1] * v[1] + v[2] * v[2] + v[3] * v[3];
#pragma unroll
    for (int d = 1; d < 64; d <<= 1) {
        s1 += __shfl_xor(s1, d, 64);
        s2 += __shfl_xor(s2, d, 64);
    }
    if (l == 0) { w1[w] = s1; w2[w] = s2; }
    __syncthreads();
    s1 = w1[0] + w1[1] + w1[2] + w1[3];
    s2 = w2[0] + w2[1] + w2[2] + w2[3];
    const float mu = s1 * (1.f / Ev);
    const float var = s2 * (1.f / Ev) - mu * mu;
    const float rinv = rsqrtf(fmaxf(var, 0.f) + 1e-5f);
    float4 gv = *(const float4*)(g + c0);
    float4 bv = *(const float4*)(bta + c0);
    float y[4];
    y[0] = (v[0] - mu) * rinv * gv.x + bv.x;
    y[1] = (v[1] - mu) * rinv * gv.y + bv.y;
    y[2] = (v[2] - mu) * rinv * gv.z + bv.z;
    y[3] = (v[3] - mu) * rinv * gv.w + bv.w;
    if (OUTF32) {
        float4 ow = {y[0], y[1], y[2], y[3]};
        *(float4*)((float*)out + (size_t)row * Ev + c0) = ow;
    } else {
        uint2 ow = {pack2(y[0], y[1]), pack2(y[2], y[3])};
        *(uint2*)((u16*)out + (size_t)row * Ev + c0) = ow;
    }
}

extern "C" void kernel_launch(void* const* d_in, const int* in_sizes, int n_in,
                              void* d_out, int out_size, void* d_ws, size_t ws_size,
                              hipStream_t stream) {
    const float* x    = (const float*)d_in[0];
    const float* ctx  = (const float*)d_in[1];
    const int*   lens = (const int*)d_in[2];
    const float* Wq1 = (const float*)d_in[4];
    const float* Wk1 = (const float*)d_in[5];
    const float* Wv1 = (const float*)d_in[6];
    const float* Wq2 = (const float*)d_in[7];
    const float* Wk2 = (const float*)d_in[8];
    const float* Wv2 = (const float*)d_in[9];
    const float* g1 = (const float*)d_in[10], *b1 = (const float*)d_in[11];
    const float* g2 = (const float*)d_in[12], *b2 = (const float*)d_in[13];
    const float* g3 = (const float*)d_in[14], *b3 = (const float*)d_in[15];
    const float* fc1w = (const float*)d_in[16], *fc1b = (const float*)d_in[17];
    const float* fc2w = (const float*)d_in[18], *fc2b = (const float*)d_in[19];

    const size_t WSZ = (size_t)Ev * Ev;
    const size_t MM  = (size_t)Mv * Ev;
    u16* WT = (u16*)d_ws;                // q1,k1,v1,q2,k2,v2,f1,f2 contiguous
    u16* Wtq1 = WT + 0 * WSZ;
    u16* Wtq2 = WT + 3 * WSZ;            // q2|k2|v2 contiguous -> one 24-wide pass
    u16* Wtf1 = WT + 6 * WSZ, *Wtf2 = WT + 7 * WSZ;
    u16* B1 = WT + 8 * WSZ;
    u16* B2 = B1 + MM;
    u16* B3 = B2 + MM;
    u16* B4 = B3 + MM;
    u16* xb = (u16*)d_out;               // bf16 x/ctx parked in d_out until final LN
    u16* cb = xb + MM;

    dim3 gP(24576), gW(24, 64), gG1(8, 64), gA(8, Hv, Bv), gL(Mv);

    prep_k<<<gP, 256, 0, stream>>>(x, ctx, Wq1, Wk1, Wv1, Wq2, Wk2, Wv2, fc1w, fc2w,
                                   xb, cb, WT);

    // self-attention (causal): fused Q/K/V^T projection, then flash
    mgemm<0, 0, 2><<<gW, 256, 0, stream>>>(xb, Wtq1, nullptr, B1, B2, B3, lens, nullptr);
    mattn<1><<<gA, 256, 0, stream>>>(B1, B2, B3, lens);                 // Z1 -> B1
    ln_k<0, 0><<<gL, 256, 0, stream>>>(x, B1, g1, b1, B2);              // X1 -> B2

    // cross-attention: fused Q2/K2 (from ctx) + V2^T (from X1) in ONE pass
    mgemm<0, 0, 2><<<gW, 256, 0, stream>>>(cb, Wtq2, nullptr, B1, B3, B4, lens, B2);
    mattn<0><<<gA, 256, 0, stream>>>(B1, B3, B4, lens);                 // Z2 -> B1
    ln_k<1, 0><<<gL, 256, 0, stream>>>(B2, B1, g2, b2, B3);             // X2 -> B3

    // FFN
    mgemm<1, 1, -1><<<gG1, 256, 0, stream>>>(B3, Wtf1, fc1b, B1, nullptr, nullptr, lens, nullptr); // H
    mgemm<1, 0, -1><<<gG1, 256, 0, stream>>>(B1, Wtf2, fc2b, B2, nullptr, nullptr, lens, nullptr); // Z3
    ln_k<1, 1><<<gL, 256, 0, stream>>>(B3, B2, g3, b3, d_out);          // final (fp32)
}

// Round 10
// 511.793 us; speedup vs baseline: 1.2927x; 1.0023x over previous
//
#include <hip/hip_runtime.h>

// decoderLayer B=8, L=1024, E=1024, H=16, dk=64. fp32 I/O, bf16 internals,
// fp32 accum via bf16 MFMA 16x16x32. This round: SINGLE change vs round 9 --
// removed the three FENCE() compiler clobbers from mgemm's K-loop. Round-9
// A/B proved the same clobbers cost ~10us/dispatch in mattn (85 -> <78);
// round-2's fence-free mgemm with the identical vmcnt/barrier pattern was
// measured correct at 75.5us. The s_waitcnt asm's "memory" clobber is the
// ordering anchor; barrier-delimited LDS sets are address-disjoint.
// mattn (round-2 form, no fences), prep, ln, fused launcher: unchanged.

typedef unsigned short u16;
typedef unsigned int u32;
typedef __attribute__((ext_vector_type(8))) short bf16x8;
typedef __attribute__((ext_vector_type(4))) float f32x4;

#define Bv 8
#define Lv 1024
#define Ev 1024
#define Hv 16
#define DKv 64
#define Mv (Bv * Lv)

#if defined(__has_builtin)
# if __has_builtin(__builtin_amdgcn_global_load_lds)
#  define HAS_GLL 1
# endif
#endif
#ifndef HAS_GLL
# define HAS_GLL 0
#endif

#if HAS_GLL
__device__ __forceinline__ void gll16(const u16* g, u16* l) {
    __builtin_amdgcn_global_load_lds(
        (const __attribute__((address_space(1))) void*)(unsigned long long)(g),
        (__attribute__((address_space(3))) void*)(unsigned)(unsigned long long)(l),
        16, 0, 0);
}
#endif

__device__ __forceinline__ u16 f2bf(float f) {
    u32 u = __float_as_uint(f);
    u += 0x7fffu + ((u >> 16) & 1u);
    return (u16)(u >> 16);
}
__device__ __forceinline__ u32 pack2(float a, float b) {
    u32 ua = __float_as_uint(a); ua += 0x7fffu + ((ua >> 16) & 1u);
    u32 ub = __float_as_uint(b); ub += 0x7fffu + ((ub >> 16) & 1u);
    return (ua >> 16) | (ub & 0xffff0000u);
}
__device__ __forceinline__ float bf_lo(u32 u) { return __uint_as_float(u << 16); }
__device__ __forceinline__ float bf_hi(u32 u) { return __uint_as_float(u & 0xffff0000u); }

// ---- fused prep: conv x, conv ctx, 6 attn-weight transposes, 2 fc transposes.
//      Routed by blockIdx.x; 256 threads. ----
__global__ __launch_bounds__(256) void prep_k(
    const float* __restrict__ x, const float* __restrict__ ctx,
    const float* __restrict__ wq1, const float* __restrict__ wk1, const float* __restrict__ wv1,
    const float* __restrict__ wq2, const float* __restrict__ wk2, const float* __restrict__ wv2,
    const float* __restrict__ f1, const float* __restrict__ f2,
    u16* __restrict__ xb, u16* __restrict__ cb, u16* __restrict__ WT) {
    const int id = blockIdx.x, t = threadIdx.x;
    if (id < 16384) { // conv x / ctx
        const float* s = (id < 8192) ? x : ctx;
        u16* d = (id < 8192) ? xb : cb;
        const int i4 = ((id & 8191) * 256 + t) * 4;
        float4 v = *(const float4*)(s + i4);
        uint2 o = {pack2(v.x, v.y), pack2(v.z, v.w)};
        *(uint2*)(d + i4) = o;
        return;
    }
    __shared__ float tl[32][33];
    const int tx = t & 31, ty = t >> 5;
    if (id < 16384 + 6144) { // attn weight (H,E,dk) -> Wt[h*64+d][e]
        const int wi = (id - 16384) >> 10;
        const int tile = (id - 16384) & 1023;
        const float* s = (wi == 0) ? wq1 : (wi == 1) ? wk1 : (wi == 2) ? wv1
                       : (wi == 3) ? wq2 : (wi == 4) ? wk2 : wv2;
        u16* d = WT + (size_t)wi * Ev * Ev;
        const int h = tile >> 6, rem = tile & 63;
        const int d0 = (rem & 1) * 32, e0 = (rem >> 1) * 32;
#pragma unroll
        for (int i = 0; i < 4; i++)
            tl[ty + i * 8][tx] = s[(size_t)h * Ev * DKv + (size_t)(e0 + ty + i * 8) * DKv + d0 + tx];
        __syncthreads();
#pragma unroll
        for (int i = 0; i < 4; i++)
            d[(size_t)(h * DKv + d0 + ty + i * 8) * Ev + e0 + tx] = f2bf(tl[tx][ty + i * 8]);
    } else { // fc weight (E,E)[k][n] -> Wt[n][k]
        const int wi = (id - 16384 - 6144) >> 10;
        const int tile = (id - 16384 - 6144) & 1023;
        const float* s = wi ? f2 : f1;
        u16* d = WT + (size_t)(6 + wi) * Ev * Ev;
        const int n0 = (tile & 31) * 32, k0 = (tile >> 5) * 32;
#pragma unroll
        for (int i = 0; i < 4; i++)
            tl[ty + i * 8][tx] = s[(size_t)(k0 + ty + i * 8) * Ev + n0 + tx];
        __syncthreads();
#pragma unroll
        for (int i = 0; i < 4; i++)
            d[(size_t)(n0 + ty + i * 8) * Ev + k0 + tx] = f2bf(tl[tx][ty + i * 8]);
    }
}

// ---- MFMA GEMM, 128x128 tile, BK=32, 32 KiB LDS dbuf -> 4 blocks/CU.
//      Distance-2 counted-vmcnt pipeline, NO compiler fences (round-2
//      precedent: same pattern measured correct; fences cost ~10us). ----
template <int BIAS, int RELU, int TRANSW>
__global__ __launch_bounds__(256, 4) void mgemm(const u16* __restrict__ A,
                                                const u16* __restrict__ Wt,
                                                const float* __restrict__ bias,
                                                u16* __restrict__ O0, u16* __restrict__ O1,
                                                u16* __restrict__ O2,
                                                const int* __restrict__ lens,
                                                const u16* __restrict__ A2) {
    __shared__ u16 Alds[2][8 * 512];
    __shared__ u16 Blds[2][8 * 512];
    const int tid = threadIdx.x;
    const int w = tid >> 6, l = tid & 63;
    const int lc = l & 15, lq = l >> 4;
    const int row0 = blockIdx.y * 128, col0 = blockIdx.x * 128;
    const int which = col0 >> 10, colL = col0 & 1023;
    u16* C = (which == 0) ? O0 : (which == 1 ? O1 : O2);
    const bool tr = (TRANSW == which);
    const u16* Aop = (A2 != nullptr && which == 2) ? A2 : A;

    int len = lens[row0 >> 10];
    len = min(max(len, 0), Lv);
    if ((row0 & (Lv - 1)) >= len) { // whole 128-row block masked -> zeros
        const int rr = tid >> 1, cc = (tid & 1) * 64;
        u16* p = tr ? C + (size_t)(colL + rr) * Mv + row0 + cc
                    : C + (size_t)(row0 + rr) * Ev + colL + cc;
        uint4 z4 = {0u, 0u, 0u, 0u};
#pragma unroll
        for (int i = 0; i < 8; i++) *(uint4*)(p + i * 8) = z4;
        return;
    }

    const int wm4 = (w >> 1) * 4, wn4 = (w & 1) * 4;
    f32x4 acc[4][4];
#pragma unroll
    for (int i = 0; i < 4; i++)
#pragma unroll
        for (int j = 0; j < 4; j++) acc[i][j] = (f32x4){0.f, 0.f, 0.f, 0.f};

    // wave w stages subtiles {2w, 2w+1} of A and B (16 rows x 32 k each)
    const u16* Ag[2]; const u16* Bg[2];
    int lof[2];
#pragma unroll
    for (int i = 0; i < 2; i++) {
        const int s = 2 * w + i;
        Ag[i] = Aop + (size_t)(row0 + s * 16 + lc) * Ev + lq * 8;
        Bg[i] = Wt  + (size_t)(col0 + s * 16 + lc) * Ev + lq * 8;
        lof[i] = s * 512;
    }

#if HAS_GLL
    // prologue: stage K-tiles 0 and 1 (4 gll16 each; per-wave vmcnt = 8)
#pragma unroll
    for (int i = 0; i < 2; i++) { gll16(Ag[i], &Alds[0][lof[i]]); gll16(Bg[i], &Blds[0][lof[i]]); }
#pragma unroll
    for (int i = 0; i < 2; i++) { gll16(Ag[i] + 32, &Alds[1][lof[i]]); gll16(Bg[i] + 32, &Blds[1][lof[i]]); }

    for (int t = 0; t < 32; ++t) {
        const int p = t & 1;
        // wait for tile t's 4 loads; tile t+1's 4 stay in flight (except tail)
        if (t < 31) asm volatile("s_waitcnt vmcnt(4)" ::: "memory");
        else        asm volatile("s_waitcnt vmcnt(0)" ::: "memory");
        __builtin_amdgcn_s_barrier();   // all waves' tile-t loads published
        bf16x8 af[4], bfr[4];
#pragma unroll
        for (int mt = 0; mt < 4; mt++)
            af[mt] = *(const bf16x8*)(&Alds[p][(wm4 + mt) * 512 + l * 8]);
#pragma unroll
        for (int nt = 0; nt < 4; nt++)
            bfr[nt] = *(const bf16x8*)(&Blds[p][(wn4 + nt) * 512 + l * 8]);
#pragma unroll
        for (int mt = 0; mt < 4; mt++)
#pragma unroll
            for (int nt = 0; nt < 4; nt++)
                acc[mt][nt] = __builtin_amdgcn_mfma_f32_16x16x32_bf16(
                    af[mt], bfr[nt], acc[mt][nt], 0, 0, 0);
        __builtin_amdgcn_s_barrier();   // all reads of buf[p] done
        if (t < 30) {                   // stage tile t+2 into freed buf[p]
            const int ko = (t + 2) * 32;
#pragma unroll
            for (int i = 0; i < 2; i++) {
                gll16(Ag[i] + ko, &Alds[p][lof[i]]);
                gll16(Bg[i] + ko, &Blds[p][lof[i]]);
            }
        }
    }
#else
    // fallback (non-gfx950): single-buffer sync staging
    for (int t = 0; t < 32; ++t) {
        const int ko = t * 32;
#pragma unroll
        for (int i = 0; i < 2; i++) {
            *(uint4*)(&Alds[0][lof[i] + l * 8]) = *(const uint4*)(Ag[i] + ko);
            *(uint4*)(&Blds[0][lof[i] + l * 8]) = *(const uint4*)(Bg[i] + ko);
        }
        __syncthreads();
        bf16x8 af[4], bfr[4];
#pragma unroll
        for (int mt = 0; mt < 4; mt++)
            af[mt] = *(const bf16x8*)(&Alds[0][(wm4 + mt) * 512 + l * 8]);
#pragma unroll
        for (int nt = 0; nt < 4; nt++)
            bfr[nt] = *(const bf16x8*)(&Blds[0][(wn4 + nt) * 512 + l * 8]);
#pragma unroll
        for (int mt = 0; mt < 4; mt++)
#pragma unroll
            for (int nt = 0; nt < 4; nt++)
                acc[mt][nt] = __builtin_amdgcn_mfma_f32_16x16x32_bf16(
                    af[mt], bfr[nt], acc[mt][nt], 0, 0, 0);
        __syncthreads();
    }
#endif

    float bv[4];
#pragma unroll
    for (int nt = 0; nt < 4; nt++)
        bv[nt] = BIAS ? bias[colL + wn4 * 16 + nt * 16 + lc] : 0.f;

#pragma unroll
    for (int mt = 0; mt < 4; mt++) {
        const int rowb = row0 + wm4 * 16 + mt * 16 + lq * 4;
#pragma unroll
        for (int nt = 0; nt < 4; nt++) {
            const int col = colL + wn4 * 16 + nt * 16 + lc;
            float v[4];
#pragma unroll
            for (int r = 0; r < 4; r++) {
                float xv = acc[mt][nt][r] + bv[nt];
                if (RELU) xv = fmaxf(xv, 0.f);
                v[r] = (((rowb + r) & (Lv - 1)) >= len) ? 0.f : xv;
            }
            if (tr) {
                uint2 o = {pack2(v[0], v[1]), pack2(v[2], v[3])};
                *(uint2*)(C + (size_t)col * Mv + rowb) = o;
            } else {
#pragma unroll
                for (int r = 0; r < 4; r++)
                    C[(size_t)(rowb + r) * Ev + col] = f2bf(v[r]);
            }
        }
    }
}

// ---- MFMA flash attention. 128 q/block, 4 waves x 32 q (2 m-tiles), 128-key
//      tiles, K/V double-buffered with counted-vmcnt (distance-1: issue stage
//      t+1, vmcnt(8), barrier, compute, barrier), P fragment-ordered LDS,
//      online softmax. Round-2 form: NO compiler fences. ----
template <int CAUSAL>
__global__ __launch_bounds__(256) void mattn(u16* __restrict__ QZ,
                                             const u16* __restrict__ K,
                                             const u16* __restrict__ VT,
                                             const int* __restrict__ lens) {
    __shared__ u16 Kt[2][16 * 512];
    __shared__ u16 Vt[2][16 * 512];
    __shared__ u16 Pt[4 * 4 * 512];
    const int b = blockIdx.z, h = blockIdx.y, qb = blockIdx.x;
    const int q0 = qb * 128;
    const int tid = threadIdx.x;
    const int w = tid >> 6, l = tid & 63;
    const int lc = l & 15, lq = l >> 4;
    int len = lens[b];
    len = min(max(len, 0), Lv);

    if (q0 >= len) {
        const int zr = tid >> 1, zc = (tid & 1) * 32;
        uint4 z4 = {0u, 0u, 0u, 0u};
        uint4* p = (uint4*)(QZ + (size_t)(b * Lv + q0 + zr) * Ev + h * DKv + zc);
        p[0] = z4; p[1] = z4; p[2] = z4; p[3] = z4;
        return;
    }

    bf16x8 qf[2][2];
#pragma unroll
    for (int mt = 0; mt < 2; mt++)
#pragma unroll
        for (int k2 = 0; k2 < 2; k2++)
            qf[mt][k2] = *(const bf16x8*)(QZ + (size_t)(b * Lv + q0 + w * 32 + mt * 16 + lc) * Ev +
                                          h * DKv + k2 * 32 + lq * 8);

    f32x4 of[2][4];
#pragma unroll
    for (int mt = 0; mt < 2; mt++)
#pragma unroll
        for (int nd = 0; nd < 4; nd++) of[mt][nd] = (f32x4){0.f, 0.f, 0.f, 0.f};
    float mrow[2][4], lrow[2][4];
#pragma unroll
    for (int mt = 0; mt < 2; mt++)
#pragma unroll
        for (int r = 0; r < 4; r++) { mrow[mt][r] = -1e30f; lrow[mt][r] = 0.f; }

    const u16* Kg[4]; const u16* Vg[4];
    int kof[4], vof[4];
#pragma unroll
    for (int i = 0; i < 4; i++) {
        const int k16 = 2 * w + (i >> 1), d32 = i & 1;
        Kg[i] = K + (size_t)(b * Lv + k16 * 16 + lc) * Ev + h * DKv + d32 * 32 + lq * 8;
        kof[i] = (k16 * 2 + d32) * 512;
        Vg[i] = VT + (size_t)(h * DKv + w * 16 + lc) * Mv + b * Lv + i * 32 + lq * 8;
        vof[i] = (w * 4 + i) * 512;
    }
    u16* Pw = Pt + w * 2048;

    const int jend = CAUSAL ? min(len, q0 + 128) : len;
    const int ntiles = (jend + 127) >> 7;

#if HAS_GLL
#pragma unroll
    for (int i = 0; i < 4; i++) {
        gll16(Kg[i], &Kt[0][kof[i]]);
        gll16(Vg[i], &Vt[0][vof[i]]);
    }
#endif
#if !HAS_GLL
#pragma unroll
    for (int i = 0; i < 4; i++) {
        *(uint4*)(&Kt[0][kof[i] + l * 8]) = *(const uint4*)Kg[i];
        *(uint4*)(&Vt[0][vof[i] + l * 8]) = *(const uint4*)Vg[i];
    }
    __syncthreads();
#endif

    for (int kt = 0; kt < ntiles; kt++) {
        const int p = kt & 1;
        const int koff = kt * 128;
#if HAS_GLL
        if (kt + 1 < ntiles) {
            const int knext = koff + 128;
#pragma unroll
            for (int i = 0; i < 4; i++) {
                gll16(Kg[i] + (size_t)knext * Ev, &Kt[p ^ 1][kof[i]]);
                gll16(Vg[i] + knext, &Vt[p ^ 1][vof[i]]);
            }
            asm volatile("s_waitcnt vmcnt(8)" ::: "memory"); // tile kt done
        } else {
            asm volatile("s_waitcnt vmcnt(0)" ::: "memory");
        }
        __builtin_amdgcn_s_barrier();   // all waves' tile-kt loads published
#else
        if (kt > 0) {
            const int kprev = koff;
#pragma unroll
            for (int i = 0; i < 4; i++) {
                *(uint4*)(&Kt[p][kof[i] + l * 8]) = *(const uint4*)(Kg[i] + (size_t)kprev * Ev);
                *(uint4*)(&Vt[p][vof[i] + l * 8]) = *(const uint4*)(Vg[i] + kprev);
            }
            __syncthreads();
        }
#endif
        const u16* Kb = &Kt[p][0];
        const u16* Vb = &Vt[p][0];

        f32x4 sf[2][8];
#pragma unroll
        for (int nt = 0; nt < 8; nt++) {
            bf16x8 kf0 = *(const bf16x8*)(Kb + (nt * 2 + 0) * 512 + l * 8);
            bf16x8 kf1 = *(const bf16x8*)(Kb + (nt * 2 + 1) * 512 + l * 8);
#pragma unroll
            for (int mt = 0; mt < 2; mt++) {
                f32x4 s = (f32x4){0.f, 0.f, 0.f, 0.f};
                s = __builtin_amdgcn_mfma_f32_16x16x32_bf16(qf[mt][0], kf0, s, 0, 0, 0);
                s = __builtin_amdgcn_mfma_f32_16x16x32_bf16(qf[mt][1], kf1, s, 0, 0, 0);
                sf[mt][nt] = s;
            }
        }

        float alpha[2][4];
#pragma unroll
        for (int mt = 0; mt < 2; mt++) {
            float tmax[4] = {-1e30f, -1e30f, -1e30f, -1e30f};
#pragma unroll
            for (int nt = 0; nt < 8; nt++) {
                const int jj = koff + nt * 16 + lc;
                const bool jv = jj < len;
#pragma unroll
                for (int r = 0; r < 4; r++) {
                    const int iq = q0 + w * 32 + mt * 16 + lq * 4 + r;
                    const bool valid = jv && (!CAUSAL || jj <= iq);
                    float e = valid ? sf[mt][nt][r] * 0.125f : -1e30f;
                    sf[mt][nt][r] = e;
                    tmax[r] = fmaxf(tmax[r], e);
                }
            }
#pragma unroll
            for (int r = 0; r < 4; r++) {
#pragma unroll
                for (int d = 1; d < 16; d <<= 1)
                    tmax[r] = fmaxf(tmax[r], __shfl_xor(tmax[r], d, 64));
            }
            float psum[4];
#pragma unroll
            for (int r = 0; r < 4; r++) {
                const float mn = fmaxf(mrow[mt][r], tmax[r]);
                alpha[mt][r] = __expf(mrow[mt][r] - mn);
                mrow[mt][r] = mn;
                psum[r] = 0.f;
            }
#pragma unroll
            for (int nt = 0; nt < 8; nt++)
#pragma unroll
                for (int r = 0; r < 4; r++) {
                    float p2 = __expf(sf[mt][nt][r] - mrow[mt][r]);
                    sf[mt][nt][r] = p2;
                    psum[r] += p2;
                }
#pragma unroll
            for (int r = 0; r < 4; r++) {
#pragma unroll
                for (int d = 1; d < 16; d <<= 1) psum[r] += __shfl_xor(psum[r], d, 64);
                lrow[mt][r] = lrow[mt][r] * alpha[mt][r] + psum[r];
            }
#pragma unroll
            for (int nd = 0; nd < 4; nd++)
#pragma unroll
                for (int r = 0; r < 4; r++) of[mt][nd][r] *= alpha[mt][r];
        }

#pragma unroll
        for (int mt = 0; mt < 2; mt++) {
#pragma unroll
            for (int nt = 0; nt < 8; nt++)
#pragma unroll
                for (int r = 0; r < 4; r++)
                    Pw[(nt >> 1) * 512 +
                       ((2 * (nt & 1) + (lc >> 3)) * 16 + lq * 4 + r) * 8 + (lc & 7)] =
                        f2bf(sf[mt][nt][r]);
#pragma unroll
            for (int km = 0; km < 4; km++) {
                bf16x8 pa = *(const bf16x8*)(Pw + km * 512 + l * 8);
#pragma unroll
                for (int nd = 0; nd < 4; nd++) {
                    bf16x8 vb = *(const bf16x8*)(Vb + (nd * 4 + km) * 512 + l * 8);
                    of[mt][nd] = __builtin_amdgcn_mfma_f32_16x16x32_bf16(pa, vb, of[mt][nd], 0, 0, 0);
                }
            }
        }
#if HAS_GLL
        __builtin_amdgcn_s_barrier();   // all reads of buf[p] done before overwrite
#else
        __syncthreads();
#endif
    }

#pragma unroll
    for (int mt = 0; mt < 2; mt++) {
        float inv[4];
#pragma unroll
        for (int r = 0; r < 4; r++) {
            const int iq = q0 + w * 32 + mt * 16 + lq * 4 + r;
            inv[r] = (iq < len && lrow[mt][r] > 0.f) ? (1.f / lrow[mt][r]) : 0.f;
        }
#pragma unroll
        for (int nd = 0; nd < 4; nd++)
#pragma unroll
            for (int r = 0; r < 4; r++)
                QZ[(size_t)(b * Lv + q0 + w * 32 + mt * 16 + lq * 4 + r) * Ev +
                   h * DKv + nd * 16 + lc] = f2bf(of[mt][nd][r] * inv[r]);
    }
}

// ---- residual + LayerNorm, shuffle reduction: out = LN(base + z)*g + b. ----
template <int BASEBF, int OUTF32>
__global__ __launch_bounds__(256) void ln_k(const void* __restrict__ base,
                                            const u16* __restrict__ z,
                                            const float* __restrict__ g,
                                            const float* __restrict__ bta,
                                            void* __restrict__ out) {
    __shared__ float w1[4], w2[4];
    const int row = blockIdx.x, t = threadIdx.x;
    const int w = t >> 6, l = t & 63;
    const int c0 = t * 4;
    float v[4];
    if (BASEBF) {
        uint2 bu = *(const uint2*)((const u16*)base + (size_t)row * Ev + c0);
        v[0] = bf_lo(bu.x); v[1] = bf_hi(bu.x); v[2] = bf_lo(bu.y); v[3] = bf_hi(bu.y);
    } else {
        float4 f = *(const float4*)((const float*)base + (size_t)row * Ev + c0);
        v[0] = f.x; v[1] = f.y; v[2] = f.z; v[3] = f.w;
    }
    uint2 zu = *(const uint2*)(z + (size_t)row * Ev + c0);
    v[0] += bf_lo(zu.x); v[1] += bf_hi(zu.x); v[2] += bf_lo(zu.y); v[3] += bf_hi(zu.y);
    float s1 = v[0] + v[1] + v[2] + v[3];
    float s2 = v[0] * v[0] + v[1] * v[1] + v[2] * v[2] + v[3] * v[3];
#pragma unroll
    for (int d = 1; d < 64; d <<= 1) {
        s1 += __shfl_xor(s1, d, 64);
        s2 += __shfl_xor(s2, d, 64);
    }
    if (l == 0) { w1[w] = s1; w2[w] = s2; }
    __syncthreads();
    s1 = w1[0] + w1[1] + w1[2] + w1[3];
    s2 = w2[0] + w2[1] + w2[2] + w2[3];
    const float mu = s1 * (1.f / Ev);
    const float var = s2 * (1.f / Ev) - mu * mu;
    const float rinv = rsqrtf(fmaxf(var, 0.f) + 1e-5f);
    float4 gv = *(const float4*)(g + c0);
    float4 bv = *(const float4*)(bta + c0);
    float y[4];
    y[0] = (v[0] - mu) * rinv * gv.x + bv.x;
    y[1] = (v[1] - mu) * rinv * gv.y + bv.y;
    y[2] = (v[2] - mu) * rinv * gv.z + bv.z;
    y[3] = (v[3] - mu) * rinv * gv.w + bv.w;
    if (OUTF32) {
        float4 ow = {y[0], y[1], y[2], y[3]};
        *(float4*)((float*)out + (size_t)row * Ev + c0) = ow;
    } else {
        uint2 ow = {pack2(y[0], y[1]), pack2(y[2], y[3])};
        *(uint2*)((u16*)out + (size_t)row * Ev + c0) = ow;
    }
}

extern "C" void kernel_launch(void* const* d_in, const int* in_sizes, int n_in,
                              void* d_out, int out_size, void* d_ws, size_t ws_size,
                              hipStream_t stream) {
    const float* x    = (const float*)d_in[0];
    const float* ctx  = (const float*)d_in[1];
    const int*   lens = (const int*)d_in[2];
    const float* Wq1 = (const float*)d_in[4];
    const float* Wk1 = (const float*)d_in[5];
    const float* Wv1 = (const float*)d_in[6];
    const float* Wq2 = (const float*)d_in[7];
    const float* Wk2 = (const float*)d_in[8];
    const float* Wv2 = (const float*)d_in[9];
    const float* g1 = (const float*)d_in[10], *b1 = (const float*)d_in[11];
    const float* g2 = (const float*)d_in[12], *b2 = (const float*)d_in[13];
    const float* g3 = (const float*)d_in[14], *b3 = (const float*)d_in[15];
    const float* fc1w = (const float*)d_in[16], *fc1b = (const float*)d_in[17];
    const float* fc2w = (const float*)d_in[18], *fc2b = (const float*)d_in[19];

    const size_t WSZ = (size_t)Ev * Ev;
    const size_t MM  = (size_t)Mv * Ev;
    u16* WT = (u16*)d_ws;                // q1,k1,v1,q2,k2,v2,f1,f2 contiguous
    u16* Wtq1 = WT + 0 * WSZ;
    u16* Wtq2 = WT + 3 * WSZ;            // q2|k2|v2 contiguous -> one 24-wide pass
    u16* Wtf1 = WT + 6 * WSZ, *Wtf2 = WT + 7 * WSZ;
    u16* B1 = WT + 8 * WSZ;
    u16* B2 = B1 + MM;
    u16* B3 = B2 + MM;
    u16* B4 = B3 + MM;
    u16* xb = (u16*)d_out;               // bf16 x/ctx parked in d_out until final LN
    u16* cb = xb + MM;

    dim3 gP(24576), gW(24, 64), gG1(8, 64), gA(8, Hv, Bv), gL(Mv);

    prep_k<<<gP, 256, 0, stream>>>(x, ctx, Wq1, Wk1, Wv1, Wq2, Wk2, Wv2, fc1w, fc2w,
                                   xb, cb, WT);

    // self-attention (causal): fused Q/K/V^T projection, then flash
    mgemm<0, 0, 2><<<gW, 256, 0, stream>>>(xb, Wtq1, nullptr, B1, B2, B3, lens, nullptr);
    mattn<1><<<gA, 256, 0, stream>>>(B1, B2, B3, lens);                 // Z1 -> B1
    ln_k<0, 0><<<gL, 256, 0, stream>>>(x, B1, g1, b1, B2);              // X1 -> B2

    // cross-attention: fused Q2/K2 (from ctx) + V2^T (from X1) in ONE pass
    mgemm<0, 0, 2><<<gW, 256, 0, stream>>>(cb, Wtq2, nullptr, B1, B3, B4, lens, B2);
    mattn<0><<<gA, 256, 0, stream>>>(B1, B3, B4, lens);                 // Z2 -> B1
    ln_k<1, 0><<<gL, 256, 0, stream>>>(B2, B1, g2, b2, B3);             // X2 -> B3

    // FFN
    mgemm<1, 1, -1><<<gG1, 256, 0, stream>>>(B3, Wtf1, fc1b, B1, nullptr, nullptr, lens, nullptr); // H
    mgemm<1, 0, -1><<<gG1, 256, 0, stream>>>(B1, Wtf2, fc2b, B2, nullptr, nullptr, lens, nullptr); // Z3
    ln_k<1, 1><<<gL, 256, 0, stream>>>(B3, B2, g3, b3, d_out);          // final (fp32)
}